// Round 5
// baseline (5322.973 us; speedup 1.0000x reference)
//
#include <hip/hip_runtime.h>
#include <hip/hip_bf16.h>

typedef unsigned short u16;
typedef __attribute__((ext_vector_type(8))) short bf16x8;
typedef __attribute__((ext_vector_type(4))) float f32x4;
typedef __attribute__((ext_vector_type(4))) unsigned u32x4;

static constexpr int V = 20000, H = 400, B = 16, S = 256, NSLOT = 30, T = 10, G = 3;
static constexpr int H3 = 3 * H;           // 1200
static constexpr int NB = NSLOT * B;       // 480
// encoder partition
static constexpr int ENBLK = 20;           // blocks per direction
static constexpr int ESL   = 20;           // h components per block (400/20)
static constexpr int EROWS = 64;           // padded weight rows per block
static constexpr int EKP   = 416;          // padded K
// fused decoder LDS strides
static constexpr int HP2 = 424;            // h_lds row stride (u16)
static constexpr int SCP = 260;            // scores row stride (f32)
static constexpr int PP  = 264;            // prob row stride (u16)
static constexpr int CXP = 404;            // ctx row stride (f32)
static constexpr int FUSED_LDS = 32*HP2*2 + 32*SCP*4 + 32*PP*2 + 32*CXP*4; // 129024

__device__ __forceinline__ float bf2f(u16 v) {
    union { unsigned u; float f; } x; x.u = ((unsigned)v) << 16; return x.f;
}
__device__ __forceinline__ u16 f2bf(float f) {
    union { float f; unsigned u; } x; x.f = f;
    unsigned r = x.u + 0x7fffu + ((x.u >> 16) & 1u);   // round-to-nearest-even
    return (u16)(r >> 16);
}
__device__ __forceinline__ float sigm(float v) { return 1.f / (1.f + __expf(-v)); }

// ---------------------------------------------------------------------------
// Generic batched GEMM: C[m][n] = sum_k A[m][k] * Bt[n][k]  (+bias[n])
// mode 0: plain (+bias). mode 1: C=exp(acc), atomicAdd row sums (softmax num).
// ---------------------------------------------------------------------------
__global__ __launch_bounds__(256) void gemm_bt(
    const u16* __restrict__ A, const u16* __restrict__ Bt,
    const float* __restrict__ bias, float* __restrict__ C,
    int M, int N, int K, int lda, int ldb, long long ldc,
    long long sA, long long sB, long long sC,
    int mode, float* __restrict__ rowsum)
{
    __shared__ u16 As[64][40];
    __shared__ u16 Bs[64][40];
    const int bz = blockIdx.z;
    A  += (long long)bz * sA;
    Bt += (long long)bz * sB;
    C  += (long long)bz * sC;
    const int m0 = blockIdx.x * 64, n0 = blockIdx.y * 64;
    const int tid = threadIdx.x, wave = tid >> 6, lane = tid & 63;
    const int wm = (wave >> 1) * 32, wn = (wave & 1) * 32;
    const int srow = tid >> 2, scol = (tid & 3) * 8;
    const int fr = lane & 15, kq = lane >> 4;
    f32x4 acc[2][2];
#pragma unroll
    for (int i = 0; i < 2; ++i)
#pragma unroll
        for (int j = 0; j < 2; ++j) acc[i][j] = (f32x4){0.f, 0.f, 0.f, 0.f};

    for (int k0 = 0; k0 < K; k0 += 32) {
        {
            int gr = m0 + srow, gc = k0 + scol;
            bf16x8 v;
            if (gr < M && gc + 8 <= K) {
                v = *(const bf16x8*)(A + (long long)gr * lda + gc);
            } else {
                short tmp[8];
#pragma unroll
                for (int j = 0; j < 8; ++j)
                    tmp[j] = (gr < M && gc + j < K) ? (short)A[(long long)gr * lda + gc + j] : (short)0;
                v = *(bf16x8*)tmp;
            }
            *(bf16x8*)&As[srow][scol] = v;
        }
        {
            int gr = n0 + srow, gc = k0 + scol;
            bf16x8 v;
            if (gr < N && gc + 8 <= K) {
                v = *(const bf16x8*)(Bt + (long long)gr * ldb + gc);
            } else {
                short tmp[8];
#pragma unroll
                for (int j = 0; j < 8; ++j)
                    tmp[j] = (gr < N && gc + j < K) ? (short)Bt[(long long)gr * ldb + gc + j] : (short)0;
                v = *(bf16x8*)tmp;
            }
            *(bf16x8*)&Bs[srow][scol] = v;
        }
        __syncthreads();
        bf16x8 af[2], bfr[2];
#pragma unroll
        for (int i = 0; i < 2; ++i) af[i]  = *(const bf16x8*)&As[wm + i * 16 + fr][kq * 8];
#pragma unroll
        for (int j = 0; j < 2; ++j) bfr[j] = *(const bf16x8*)&Bs[wn + j * 16 + fr][kq * 8];
#pragma unroll
        for (int i = 0; i < 2; ++i)
#pragma unroll
            for (int j = 0; j < 2; ++j)
                acc[i][j] = __builtin_amdgcn_mfma_f32_16x16x32_bf16(af[i], bfr[j], acc[i][j], 0, 0, 0);
        __syncthreads();
    }

#pragma unroll
    for (int i = 0; i < 2; ++i)
#pragma unroll
        for (int j = 0; j < 2; ++j) {
            int col = n0 + wn + j * 16 + fr;
            float bv = (bias != nullptr && col < N) ? bias[col] : 0.f;
#pragma unroll
            for (int r = 0; r < 4; ++r) {
                int row = m0 + wm + i * 16 + kq * 4 + r;
                bool ok = (row < M) && (col < N);
                float v = acc[i][j][r] + bv;
                if (mode == 1) { v = ok ? __expf(v) : 0.f; acc[i][j][r] = v; }
                if (ok) C[(long long)row * ldc + col] = v;
            }
        }
    if (mode == 1) {
#pragma unroll
        for (int i = 0; i < 2; ++i)
#pragma unroll
            for (int r = 0; r < 4; ++r) {
                float s = acc[i][0][r] + acc[i][1][r];
                s += __shfl_xor(s, 1); s += __shfl_xor(s, 2);
                s += __shfl_xor(s, 4); s += __shfl_xor(s, 8);
                if (fr == 0) {
                    int row = m0 + wm + i * 16 + kq * 4 + r;
                    if (row < M) atomicAdd(&rowsum[row], s);
                }
            }
    }
}

// ---------------------------------------------------------------------------
// small utility kernels
// ---------------------------------------------------------------------------
__global__ void cvt_bf16_kernel(const float* __restrict__ src, u16* __restrict__ dst, int n) {
    for (int i = blockIdx.x * blockDim.x + threadIdx.x; i < n; i += gridDim.x * blockDim.x)
        dst[i] = f2bf(src[i]);
}

__global__ void cvt4_kernel(const float* __restrict__ a, const float* __restrict__ b,
                            const float* __restrict__ c, const float* __restrict__ d,
                            u16* __restrict__ da, u16* __restrict__ db,
                            u16* __restrict__ dc, u16* __restrict__ dd, int n) {
    for (int i = blockIdx.x * blockDim.x + threadIdx.x; i < n; i += gridDim.x * blockDim.x) {
        da[i] = f2bf(a[i]); db[i] = f2bf(b[i]); dc[i] = f2bf(c[i]); dd[i] = f2bf(d[i]);
    }
}

// weight prep for the distributed encoder: dst[dir][j][rloc][k], rloc = g*20+c
__global__ void prep_wenc_kernel(const float* __restrict__ whhf, const float* __restrict__ whhb,
                                 u16* __restrict__ dst) {
    int idx = blockIdx.x * 256 + threadIdx.x;
    const int total = 2 * ENBLK * EROWS * EKP;
    if (idx >= total) return;
    int k = idx % EKP; int r = idx / EKP;
    int rloc = r % EROWS; r /= EROWS;
    int j = r % ENBLK; int dir = r / ENBLK;
    u16 v = 0;
    if (k < H && rloc < 3 * ESL) {
        int g = rloc / ESL, c = rloc % ESL;
        const float* W = dir ? whhb : whhf;
        v = f2bf(W[(long long)(g * H + j * ESL + c) * H + k]);
    }
    dst[idx] = v;
}

__global__ void embed_story_kernel(const int* __restrict__ story, const u16* __restrict__ embb,
                                   u16* __restrict__ xb) {
    int row = blockIdx.x;                 // row = s*16 + b
    int s = row >> 4, b = row & 15;
    int tok = story[b * S + s];
    const u16* e = embb + (long long)tok * H;
    u16* d = xb + (long long)row * H;
    for (int k = threadIdx.x; k < H; k += blockDim.x) d[k] = e[k];
}

__global__ void build_decin_kernel(const int* __restrict__ tgt, const int* __restrict__ dom,
                                   const int* __restrict__ sidx, const float* __restrict__ slt,
                                   const u16* __restrict__ embb, u16* __restrict__ decin) {
    int n = blockIdx.x, t = blockIdx.y;
    int b = n & 15, slot = n >> 4;
    u16* d = decin + ((long long)t * NB + n) * H;
    if (t == 0) {
        const float* s1 = slt + (long long)dom[slot] * H;
        const float* s2 = slt + (long long)sidx[slot] * H;
        for (int k = threadIdx.x; k < H; k += blockDim.x) d[k] = f2bf(s1[k] + s2[k]);
    } else {
        int tok = tgt[(b * NSLOT + slot) * T + (t - 1)];
        const u16* e = embb + (long long)tok * H;
        for (int k = threadIdx.x; k < H; k += blockDim.x) d[k] = e[k];
    }
}

// ---------------------------------------------------------------------------
// Distributed encoder recurrence, protocol v4 (fence-free):
//  - ALL cross-block data (hbuf) moves via relaxed AGENT-scope atomics, which
//    are serviced at the coherence point (bypass the non-coherent per-XCD L2).
//    => no acquire buffer_inv, no release buffer_wbl2, no RMW contention.
//  - publisher: hbuf atomic stores -> __syncthreads (vmcnt0 drain) ->
//    per-block flag atomic store (20 distinct addresses).
//  - reader: lanes 0..19 poll 20 flags relaxed; compiler barrier; 104 relaxed
//    u32 atomic loads feed the dual 13-deep MFMA chains.
// ---------------------------------------------------------------------------
__global__ __launch_bounds__(256) void enc_rnn4_kernel(
    const u16* __restrict__ wencp,
    const float* __restrict__ bhhf, const float* __restrict__ bhhb,
    const float* __restrict__ gif, const float* __restrict__ gib,
    const int* __restrict__ lens,
    unsigned* __restrict__ hbuf, int* __restrict__ flags,
    float* __restrict__ ysf, float* __restrict__ ysb,
    float* __restrict__ hfo, float* __restrict__ hbo)
{
    const int bid = blockIdx.x;
    const int dir = bid / ENBLK, j = bid % ENBLK;
    const float* bhh = dir ? bhhb : bhhf;
    const float* gi  = dir ? gib  : gif;
    float* ys = dir ? ysb : ysf;
    float* ho = dir ? hbo : hfo;

    __shared__ u16 wlds[EROWS * EKP];      // 53248 B
    __shared__ float ghs[EROWS * 17];      // 4352 B

    const int tid = threadIdx.x, wave = tid >> 6, lane = tid & 63;
    const int fr = lane & 15, kq = lane >> 4;

    const u16* wsrc = wencp + (long long)(dir * ENBLK + j) * EROWS * EKP;
    for (int i = tid * 8; i < EROWS * EKP; i += 256 * 8)
        *(bf16x8*)&wlds[i] = *(const bf16x8*)&wsrc[i];

    const int p0 = tid, p1 = 256 + tid;
    const bool has1 = (tid < 64);
    const int b0 = p0 / ESL, kl0 = p0 % ESL;
    const int b1 = has1 ? p1 / ESL : 0, kl1 = has1 ? p1 % ESL : 0;
    const int k0 = j * ESL;
    const int len0 = lens[b0];
    const int len1 = has1 ? lens[b1] : 0;
    const float bhr0 = bhh[k0 + kl0], bhz0 = bhh[H + k0 + kl0], bhn0 = bhh[2 * H + k0 + kl0];
    const float bhr1 = has1 ? bhh[k0 + kl1] : 0.f;
    const float bhz1 = has1 ? bhh[H + k0 + kl1] : 0.f;
    const float bhn1 = has1 ? bhh[2 * H + k0 + kl1] : 0.f;
    float h0r = 0.f, h1r = 0.f;

    int* flg = flags + dir * 32;
    unsigned* hb_d = hbuf + (long long)dir * 2 * B * EKP;
    const u16* arow = &wlds[(wave * 16 + fr) * EKP + kq * 8];
    __syncthreads();

    for (int t = 0; t < S; ++t) {
        const int s = dir ? (S - 1 - t) : t;
        const float* gbase = gi + (long long)s * B * H3;
        float gr0 = gbase[b0 * H3 + k0 + kl0];
        float gz0 = gbase[b0 * H3 + H + k0 + kl0];
        float gn0 = gbase[b0 * H3 + 2 * H + k0 + kl0];
        float gr1 = 0.f, gz1 = 0.f, gn1 = 0.f;
        if (has1) {
            gr1 = gbase[b1 * H3 + k0 + kl1];
            gz1 = gbase[b1 * H3 + H + k0 + kl1];
            gn1 = gbase[b1 * H3 + 2 * H + k0 + kl1];
        }

        f32x4 acc = (f32x4){0.f, 0.f, 0.f, 0.f};
        if (t > 0) {
            // fence-free spin: relaxed agent loads, no cache maintenance
            for (;;) {
                int v = 0x7fffffff;
                if (lane < ENBLK)
                    v = __hip_atomic_load(&flg[lane], __ATOMIC_RELAXED,
                                          __HIP_MEMORY_SCOPE_AGENT);
                if (__all(v >= t)) break;
            }
            asm volatile("" ::: "memory");   // keep hbuf reads after the poll
            const unsigned* hrow = hb_d + (long long)(t & 1) * B * EKP
                                   + (long long)fr * EKP + kq * 8;
            f32x4 acch = (f32x4){0.f, 0.f, 0.f, 0.f};
            f32x4 accl = (f32x4){0.f, 0.f, 0.f, 0.f};
#pragma unroll
            for (int kk = 0; kk < 13; ++kk) {
                unsigned a[8];
#pragma unroll
                for (int q = 0; q < 8; ++q)
                    a[q] = __hip_atomic_load(hrow + kk * 32 + q, __ATOMIC_RELAXED,
                                             __HIP_MEMORY_SCOPE_AGENT);
                union { unsigned u[4]; bf16x8 v; } hi, lo;
                hi.u[0] = __builtin_amdgcn_perm(a[1], a[0], 0x05040100u);
                hi.u[1] = __builtin_amdgcn_perm(a[3], a[2], 0x05040100u);
                hi.u[2] = __builtin_amdgcn_perm(a[5], a[4], 0x05040100u);
                hi.u[3] = __builtin_amdgcn_perm(a[7], a[6], 0x05040100u);
                lo.u[0] = __builtin_amdgcn_perm(a[1], a[0], 0x07060302u);
                lo.u[1] = __builtin_amdgcn_perm(a[3], a[2], 0x07060302u);
                lo.u[2] = __builtin_amdgcn_perm(a[5], a[4], 0x07060302u);
                lo.u[3] = __builtin_amdgcn_perm(a[7], a[6], 0x07060302u);
                bf16x8 av = *(const bf16x8*)(arow + kk * 32);
                acch = __builtin_amdgcn_mfma_f32_16x16x32_bf16(av, hi.v, acch, 0, 0, 0);
                accl = __builtin_amdgcn_mfma_f32_16x16x32_bf16(av, lo.v, accl, 0, 0, 0);
            }
            acc = acch + accl;
        }
#pragma unroll
        for (int r = 0; r < 4; ++r) ghs[(wave * 16 + kq * 4 + r) * 17 + fr] = acc[r];
        __syncthreads();

        unsigned* hpub = hb_d + (long long)((t + 1) & 1) * B * EKP;
        {
            float ghr = ghs[kl0 * 17 + b0];
            float ghz = ghs[(ESL + kl0) * 17 + b0];
            float ghn = ghs[(2 * ESL + kl0) * 17 + b0];
            float rg = sigm(gr0 + ghr + bhr0);
            float zg = sigm(gz0 + ghz + bhz0);
            float ng = tanhf(gn0 + rg * (ghn + bhn0));
            float hn = (1.f - zg) * ng + zg * h0r;
            bool msk = s < len0;
            float y = msk ? hn : 0.f;
            if (msk) h0r = hn;
            ys[((long long)(b0 * S + s)) * H + k0 + kl0] = y;   // plain cached store
            u16 hi = f2bf(h0r);
            unsigned packed = (unsigned)hi | ((unsigned)f2bf(h0r - bf2f(hi)) << 16);
            __hip_atomic_store(&hpub[b0 * EKP + k0 + kl0], packed, __ATOMIC_RELAXED,
                               __HIP_MEMORY_SCOPE_AGENT);
        }
        if (has1) {
            float ghr = ghs[kl1 * 17 + b1];
            float ghz = ghs[(ESL + kl1) * 17 + b1];
            float ghn = ghs[(2 * ESL + kl1) * 17 + b1];
            float rg = sigm(gr1 + ghr + bhr1);
            float zg = sigm(gz1 + ghz + bhz1);
            float ng = tanhf(gn1 + rg * (ghn + bhn1));
            float hn = (1.f - zg) * ng + zg * h1r;
            bool msk = s < len1;
            float y = msk ? hn : 0.f;
            if (msk) h1r = hn;
            ys[((long long)(b1 * S + s)) * H + k0 + kl1] = y;
            u16 hi = f2bf(h1r);
            unsigned packed = (unsigned)hi | ((unsigned)f2bf(h1r - bf2f(hi)) << 16);
            __hip_atomic_store(&hpub[b1 * EKP + k0 + kl1], packed, __ATOMIC_RELAXED,
                               __HIP_MEMORY_SCOPE_AGENT);
        }
        // barrier: compiler emits s_waitcnt vmcnt(0) before s_barrier, so all
        // waves' agent-scope publish stores are at the coherence point.
        __syncthreads();
        if (tid == 0)
            __hip_atomic_store(&flg[j], t + 1, __ATOMIC_RELAXED,
                               __HIP_MEMORY_SCOPE_AGENT);
    }
    ho[b0 * H + k0 + kl0] = h0r;
    if (has1) ho[b1 * H + k0 + kl1] = h1r;
}

// E = ys_f + ys_b (bf16, [b][s][k]) and ET (bf16, [b][k][s])
__global__ void packE_kernel(const float* __restrict__ ysf, const float* __restrict__ ysb,
                             u16* __restrict__ E, u16* __restrict__ ET) {
    __shared__ u16 tile[32][400];
    const int b = blockIdx.x, s0 = blockIdx.y * 32;
    for (int si = 0; si < 32; ++si) {
        const long long base = ((long long)b * S + s0 + si) * H;
        for (int k = threadIdx.x; k < H; k += blockDim.x) {
            u16 v = f2bf(ysf[base + k] + ysb[base + k]);
            E[base + k] = v;
            tile[si][k] = v;
        }
    }
    __syncthreads();
    for (int idx = threadIdx.x; idx < 32 * H; idx += blockDim.x) {
        int k = idx >> 5, si = idx & 31;
        ET[((long long)b * H + k) * S + s0 + si] = tile[si][k];
    }
}

__global__ void h0_kernel(const float* __restrict__ hf, const float* __restrict__ hb,
                          float* __restrict__ hf32, u16* __restrict__ hnk) {
    int n = blockIdx.x, b = n & 15;
    for (int k = threadIdx.x; k < H; k += blockDim.x) {
        float v = hf[b * H + k] + hb[b * H + k];
        hf32[(long long)n * H + k] = v;
        hnk[(long long)n * H + k] = f2bf(v);
    }
}

// ---------------------------------------------------------------------------
// Fused decoder step: block = batch b (16 blocks, 512 threads, dynamic LDS).
// ---------------------------------------------------------------------------
__global__ __launch_bounds__(512) void fused_step_kernel(
    const float* __restrict__ dgi, const float* __restrict__ dgh,
    float* __restrict__ hf32, u16* __restrict__ hnk,
    const u16* __restrict__ decinb,
    const u16* __restrict__ Eb, const u16* __restrict__ ETb,
    const int* __restrict__ lens,
    const float* __restrict__ Wr, const float* __restrict__ br,
    const float* __restrict__ Wg, const float* __restrict__ bg,
    float* __restrict__ probf, float* __restrict__ swv,
    float* __restrict__ gout, int t)
{
    extern __shared__ char smem[];
    u16*   hls = (u16*)smem;                                   // [32][HP2]
    float* scs = (float*)(smem + 32 * HP2 * 2);                // [32][SCP]
    u16*   pls = (u16*)(smem + 32 * HP2 * 2 + 32 * SCP * 4);   // [32][PP]
    float* cxs = (float*)(smem + 32 * HP2 * 2 + 32 * SCP * 4 + 32 * PP * 2); // [32][CXP]

    const int b = blockIdx.x;
    const int tid = threadIdx.x, wave = tid >> 6, lane = tid & 63;
    const int fr = lane & 15, kq = lane >> 4;
    const int len = lens[b];

    for (int i = tid; i < 32 * (HP2 - H); i += 512) {
        int r = i / (HP2 - H), c = H + i % (HP2 - H);
        hls[r * HP2 + c] = 0;
    }
    for (int i = tid; i < 2 * HP2; i += 512) hls[30 * HP2 + i] = 0;
    for (int i = tid; i < 2 * PP; i += 512) pls[30 * PP + i] = 0;

    // P0: GRU cell for the 30 slots of this batch
    for (int i = tid; i < 30 * H; i += 512) {
        int slot = i / H, k = i % H;
        int n = slot * 16 + b;
        const float* gi = dgi + ((long long)t * NB + n) * H3;
        const float* gh = dgh + (long long)n * H3;
        float r  = sigm(gi[k] + gh[k]);
        float z  = sigm(gi[H + k] + gh[H + k]);
        float nn = tanhf(gi[2 * H + k] + r * gh[2 * H + k]);
        float h  = hf32[(long long)n * H + k];
        float hn = (1.f - z) * nn + z * h;
        hf32[(long long)n * H + k] = hn;
        u16 hb = f2bf(hn);
        hnk[(long long)n * H + k] = hb;
        hls[slot * HP2 + k] = hb;
    }
    __syncthreads();

    // P1: scores[slot][s] = h . E[b][s]   (M=32, N=256, K=400)
    {
        const int nt0 = wave * 2;
        f32x4 acc[2][2];
#pragma unroll
        for (int i = 0; i < 2; ++i)
#pragma unroll
            for (int jj = 0; jj < 2; ++jj) acc[i][jj] = (f32x4){0.f, 0.f, 0.f, 0.f};
        const u16* br0 = Eb + ((long long)b * S + nt0 * 16 + fr) * H + kq * 8;
        const u16* br1 = Eb + ((long long)b * S + (nt0 + 1) * 16 + fr) * H + kq * 8;
        const u16* ar0 = hls + fr * HP2 + kq * 8;
        const u16* ar1 = hls + (16 + fr) * HP2 + kq * 8;
#pragma unroll
        for (int kk = 0; kk < 13; ++kk) {
            bf16x8 av0 = *(const bf16x8*)(ar0 + kk * 32);
            bf16x8 av1 = *(const bf16x8*)(ar1 + kk * 32);
            bf16x8 bv0, bv1;
            if (kk == 12 && kq >= 2) {
                bv0 = (bf16x8){0,0,0,0,0,0,0,0}; bv1 = bv0;
            } else {
                bv0 = *(const bf16x8*)(br0 + kk * 32);
                bv1 = *(const bf16x8*)(br1 + kk * 32);
            }
            acc[0][0] = __builtin_amdgcn_mfma_f32_16x16x32_bf16(av0, bv0, acc[0][0], 0, 0, 0);
            acc[1][0] = __builtin_amdgcn_mfma_f32_16x16x32_bf16(av1, bv0, acc[1][0], 0, 0, 0);
            acc[0][1] = __builtin_amdgcn_mfma_f32_16x16x32_bf16(av0, bv1, acc[0][1], 0, 0, 0);
            acc[1][1] = __builtin_amdgcn_mfma_f32_16x16x32_bf16(av1, bv1, acc[1][1], 0, 0, 0);
        }
#pragma unroll
        for (int i = 0; i < 2; ++i)
#pragma unroll
            for (int jj = 0; jj < 2; ++jj)
#pragma unroll
                for (int r = 0; r < 4; ++r)
                    scs[(i * 16 + kq * 4 + r) * SCP + (nt0 + jj) * 16 + fr] = acc[i][jj][r];
    }
    __syncthreads();

    // P2: softmax rows
    for (int i = 0; i < 4; ++i) {
        int row = wave * 4 + i;
        if (row >= 30) break;
        int n = row * 16 + b;
        float v[4];
        float mx = -3.0e38f;
#pragma unroll
        for (int q = 0; q < 4; ++q) {
            int s = lane + 64 * q;
            float x = (s < len) ? scs[row * SCP + s] : -3.0e38f;
            v[q] = x; mx = fmaxf(mx, x);
        }
        mx = fmaxf(mx, __shfl_xor(mx, 1));  mx = fmaxf(mx, __shfl_xor(mx, 2));
        mx = fmaxf(mx, __shfl_xor(mx, 4));  mx = fmaxf(mx, __shfl_xor(mx, 8));
        mx = fmaxf(mx, __shfl_xor(mx, 16)); mx = fmaxf(mx, __shfl_xor(mx, 32));
        float sum = 0.f;
#pragma unroll
        for (int q = 0; q < 4; ++q) {
            int s = lane + 64 * q;
            float e = (s < len) ? __expf(v[q] - mx) : 0.f;
            v[q] = e; sum += e;
        }
        sum += __shfl_xor(sum, 1);  sum += __shfl_xor(sum, 2);
        sum += __shfl_xor(sum, 4);  sum += __shfl_xor(sum, 8);
        sum += __shfl_xor(sum, 16); sum += __shfl_xor(sum, 32);
        float inv = 1.f / sum;
#pragma unroll
        for (int q = 0; q < 4; ++q) {
            int s = lane + 64 * q;
            float pr = v[q] * inv;
            pls[row * PP + s] = f2bf(pr);
            probf[(long long)n * S + s] = pr;
        }
    }
    __syncthreads();

    // P3: ctx[slot][k] = sum_s prob[slot][s] * ET[b][k][s]
    for (int nt = wave; nt < 25; nt += 8) {
        f32x4 acc0 = (f32x4){0.f,0.f,0.f,0.f}, acc1 = (f32x4){0.f,0.f,0.f,0.f};
        const u16* brow = ETb + ((long long)b * H + nt * 16 + fr) * S + kq * 8;
        const u16* ar0 = pls + fr * PP + kq * 8;
        const u16* ar1 = pls + (16 + fr) * PP + kq * 8;
#pragma unroll
        for (int kk = 0; kk < 8; ++kk) {
            bf16x8 bv  = *(const bf16x8*)(brow + kk * 32);
            bf16x8 av0 = *(const bf16x8*)(ar0 + kk * 32);
            bf16x8 av1 = *(const bf16x8*)(ar1 + kk * 32);
            acc0 = __builtin_amdgcn_mfma_f32_16x16x32_bf16(av0, bv, acc0, 0, 0, 0);
            acc1 = __builtin_amdgcn_mfma_f32_16x16x32_bf16(av1, bv, acc1, 0, 0, 0);
        }
#pragma unroll
        for (int r = 0; r < 4; ++r) {
            cxs[(kq * 4 + r) * CXP + nt * 16 + fr] = acc0[r];
            cxs[(16 + kq * 4 + r) * CXP + nt * 16 + fr] = acc1[r];
        }
    }
    __syncthreads();

    // P4: p_gen switch (+ gate at t==0)
    for (int i = 0; i < 4; ++i) {
        int slot = wave + 8 * i;
        if (slot >= 30) break;
        int n = slot * 16 + b;
        const u16* xrow = decinb + ((long long)t * NB + n) * H;
        float p = 0.f;
        for (int k = lane; k < H; k += 64)
            p += bf2f(hls[slot * HP2 + k]) * Wr[k]
               + cxs[slot * CXP + k] * Wr[H + k]
               + bf2f(xrow[k]) * Wr[2 * H + k];
        p += __shfl_xor(p, 1);  p += __shfl_xor(p, 2);
        p += __shfl_xor(p, 4);  p += __shfl_xor(p, 8);
        p += __shfl_xor(p, 16); p += __shfl_xor(p, 32);
        if (lane == 0) swv[n] = sigm(p + br[0]);
        if (t == 0) {
            for (int g = 0; g < G; ++g) {
                float q = 0.f;
                for (int k = lane; k < H; k += 64)
                    q += cxs[slot * CXP + k] * Wg[g * H + k];
                q += __shfl_xor(q, 1);  q += __shfl_xor(q, 2);
                q += __shfl_xor(q, 4);  q += __shfl_xor(q, 8);
                q += __shfl_xor(q, 16); q += __shfl_xor(q, 32);
                if (lane == 0) gout[(long long)n * G + g] = q + bg[g];
            }
        }
    }
}

__global__ void scale_kernel(float* __restrict__ out, const float* __restrict__ sw,
                             const float* __restrict__ rowsum, int t) {
    const int n = blockIdx.x;
    const float f = sw[n] / rowsum[n];
    float* row = out + ((long long)n * T + t) * V;
    const int col = blockIdx.y * 256 + threadIdx.x;
    if (col < V) row[col] *= f;
}

__global__ void scatter_kernel(float* __restrict__ out, const int* __restrict__ story,
                               const int* __restrict__ lens, const float* __restrict__ sw,
                               const float* __restrict__ probf, int t) {
    const int n = blockIdx.x, b = n & 15, s = threadIdx.x;
    if (s < lens[b]) {
        int tok = story[b * S + s];
        atomicAdd(out + ((long long)n * T + t) * V + tok,
                  (1.f - sw[n]) * probf[(long long)n * S + s]);
    }
}

// ---------------------------------------------------------------------------
extern "C" void kernel_launch(void* const* d_in, const int* in_sizes, int n_in,
                              void* d_out, int out_size, void* d_ws, size_t ws_size,
                              hipStream_t stream) {
    const int*   story = (const int*)d_in[0];
    const int*   lens  = (const int*)d_in[1];
    const int*   tgt   = (const int*)d_in[2];
    const int*   dom   = (const int*)d_in[3];
    const int*   sidx  = (const int*)d_in[4];
    const float* emb   = (const float*)d_in[5];
    const float* wihf  = (const float*)d_in[6];
    const float* whhf  = (const float*)d_in[7];
    const float* bihf  = (const float*)d_in[8];
    const float* bhhf  = (const float*)d_in[9];
    const float* wihb  = (const float*)d_in[10];
    const float* whhb  = (const float*)d_in[11];
    const float* bihb  = (const float*)d_in[12];
    const float* bhhb  = (const float*)d_in[13];
    const float* dwih  = (const float*)d_in[14];
    const float* dwhh  = (const float*)d_in[15];
    const float* dbih  = (const float*)d_in[16];
    const float* dbhh  = (const float*)d_in[17];
    const float* Wr    = (const float*)d_in[18];
    const float* br    = (const float*)d_in[19];
    const float* Wg    = (const float*)d_in[20];
    const float* bg    = (const float*)d_in[21];
    const float* slt   = (const float*)d_in[22];
    float* out = (float*)d_out;

    char* wsb = (char*)d_ws;
    size_t off = 0;
    auto alloc = [&](size_t bytes) -> char* {
        char* p = wsb + off;
        off += (bytes + 255) & ~(size_t)255;
        return p;
    };
    u16*   embb   = (u16*)alloc((size_t)V * H * 2);
    u16*   wihfb  = (u16*)alloc((size_t)H3 * H * 2);
    u16*   wihbb  = (u16*)alloc((size_t)H3 * H * 2);
    u16*   dwihb  = (u16*)alloc((size_t)H3 * H * 2);
    u16*   dwhhb  = (u16*)alloc((size_t)H3 * H * 2);
    u16*   wencp  = (u16*)alloc((size_t)2 * ENBLK * EROWS * EKP * 2);
    unsigned* hbuf = (unsigned*)alloc((size_t)2 * 2 * B * EKP * 4);
    int*   flags  = (int*)alloc((size_t)2 * 32 * 4);
    u16*   xb     = (u16*)alloc((size_t)S * B * H * 2);
    u16*   decinb = (u16*)alloc((size_t)T * NB * H * 2);
    float* gif    = (float*)alloc((size_t)S * B * H3 * 4);
    float* gib    = (float*)alloc((size_t)S * B * H3 * 4);
    float* dgi    = (float*)alloc((size_t)T * NB * H3 * 4);
    float* ysf    = (float*)alloc((size_t)B * S * H * 4);
    float* ysb    = (float*)alloc((size_t)B * S * H * 4);
    float* hfv    = (float*)alloc((size_t)B * H * 4);
    float* hbv    = (float*)alloc((size_t)B * H * 4);
    u16*   Eb     = (u16*)alloc((size_t)B * S * H * 2);
    u16*   ETb    = (u16*)alloc((size_t)B * H * S * 2);
    float* hf32   = (float*)alloc((size_t)NB * H * 4);
    u16*   hnk    = (u16*)alloc((size_t)NB * H * 2);
    float* dgh    = (float*)alloc((size_t)NB * H3 * 4);
    float* probf  = (float*)alloc((size_t)NB * S * 4);
    float* swv    = (float*)alloc((size_t)NB * 4);
    float* rowsumT = (float*)alloc((size_t)NB * T * 4);
    (void)ws_size; (void)in_sizes; (void)n_in; (void)out_size;

    auto launch_gemm = [&](const u16* A, const u16* Bt, const float* bias, float* C,
                           int M, int N, int K, int lda, int ldb, long long ldc,
                           long long sA, long long sB, long long sC, int nb,
                           int mode, float* rs) {
        dim3 g((M + 63) / 64, (N + 63) / 64, nb);
        gemm_bt<<<g, 256, 0, stream>>>(A, Bt, bias, C, M, N, K, lda, ldb, ldc,
                                       sA, sB, sC, mode, rs);
    };

    hipFuncSetAttribute((const void*)fused_step_kernel,
                        hipFuncAttributeMaxDynamicSharedMemorySize, FUSED_LDS);

    // ---- setup: casts, embeddings, input-side GEMMs -----------------------
    cvt_bf16_kernel<<<2048, 256, 0, stream>>>(emb, embb, V * H);
    cvt4_kernel<<<1024, 256, 0, stream>>>(wihf, wihb, dwih, dwhh,
                                          wihfb, wihbb, dwihb, dwhhb, H3 * H);
    {
        const int total = 2 * ENBLK * EROWS * EKP;
        prep_wenc_kernel<<<(total + 255) / 256, 256, 0, stream>>>(whhf, whhb, wencp);
    }
    embed_story_kernel<<<S * B, 256, 0, stream>>>(story, embb, xb);
    { dim3 g(NB, T); build_decin_kernel<<<g, 256, 0, stream>>>(tgt, dom, sidx, slt, embb, decinb); }

    launch_gemm(xb, wihfb, bihf, gif, S * B, H3, H, H, H, H3, 0, 0, 0, 1, 0, nullptr);
    launch_gemm(xb, wihbb, bihb, gib, S * B, H3, H, H, H, H3, 0, 0, 0, 1, 0, nullptr);
    launch_gemm(decinb, dwihb, dbih, dgi, T * NB, H3, H, H, H, H3, 0, 0, 0, 1, 0, nullptr);

    // ---- encoder recurrence (distributed, fence-free flag sync) -----------
    hipMemsetAsync(flags, 0, (size_t)2 * 32 * 4, stream);
    hipMemsetAsync(hbuf, 0, (size_t)2 * 2 * B * EKP * 4, stream);
    hipMemsetAsync(rowsumT, 0, (size_t)NB * T * 4, stream);
    enc_rnn4_kernel<<<2 * ENBLK, 256, 0, stream>>>(wencp, bhhf, bhhb, gif, gib, lens,
                                                   hbuf, flags, ysf, ysb, hfv, hbv);
    { dim3 g(B, S / 32); packE_kernel<<<g, 256, 0, stream>>>(ysf, ysb, Eb, ETb); }
    h0_kernel<<<NB, 256, 0, stream>>>(hfv, hbv, hf32, hnk);

    // ---- decoder ----------------------------------------------------------
    for (int t = 0; t < T; ++t) {
        launch_gemm(hnk, dwhhb, dbhh, dgh, NB, H3, H, H, H, H3, 0, 0, 0, 1, 0, nullptr);
        fused_step_kernel<<<16, 512, FUSED_LDS, stream>>>(
            dgi, dgh, hf32, hnk, decinb, Eb, ETb, lens, Wr, br, Wg, bg,
            probf, swv, out + (size_t)NB * T * V, t);
        launch_gemm(hnk, embb, nullptr, out + (size_t)t * V, NB, V, H, H, H,
                    (long long)T * V, 0, 0, 0, 1, 1, rowsumT + (size_t)t * NB);
        { dim3 g(NB, (V + 255) / 256); scale_kernel<<<g, 256, 0, stream>>>(out, swv, rowsumT + (size_t)t * NB, t); }
        scatter_kernel<<<NB, 256, 0, stream>>>(out, story, lens, swv, probf, t);
    }
}

// Round 6
// 3074.827 us; speedup vs baseline: 1.7311x; 1.7311x over previous
//
#include <hip/hip_runtime.h>
#include <hip/hip_bf16.h>

typedef unsigned short u16;
typedef __attribute__((ext_vector_type(8))) short bf16x8;
typedef __attribute__((ext_vector_type(4))) float f32x4;
typedef __attribute__((ext_vector_type(4))) unsigned u32x4;

static constexpr int V = 20000, H = 400, B = 16, S = 256, NSLOT = 30, T = 10, G = 3;
static constexpr int H3 = 3 * H;           // 1200
static constexpr int NB = NSLOT * B;       // 480
// encoder partition
static constexpr int ENBLK = 20;           // blocks per direction
static constexpr int ESL   = 20;           // h components per block (400/20)
static constexpr int EROWS = 64;           // padded weight rows per block
static constexpr int EKP   = 416;          // padded K
// fused decoder LDS strides
static constexpr int HP2 = 424;            // h_lds row stride (u16)
static constexpr int SCP = 260;            // scores row stride (f32)
static constexpr int PP  = 264;            // prob row stride (u16)
static constexpr int CXP = 404;            // ctx row stride (f32)
static constexpr int FUSED_LDS = 32*HP2*2 + 32*SCP*4 + 32*PP*2 + 32*CXP*4; // 129024

__device__ __forceinline__ float bf2f(u16 v) {
    union { unsigned u; float f; } x; x.u = ((unsigned)v) << 16; return x.f;
}
__device__ __forceinline__ u16 f2bf(float f) {
    union { float f; unsigned u; } x; x.f = f;
    unsigned r = x.u + 0x7fffu + ((x.u >> 16) & 1u);   // round-to-nearest-even
    return (u16)(r >> 16);
}
__device__ __forceinline__ float sigm(float v) { return 1.f / (1.f + __expf(-v)); }

// ---------------------------------------------------------------------------
// Generic batched GEMM: C[m][n] = sum_k A[m][k] * Bt[n][k]  (+bias[n])
// mode 0: plain (+bias). mode 1: C=exp(acc)+rowsum, ldc layout.
// mode 2: C=exp(acc)+rowsum, vocab layout: row=t*NB+n -> C[((n*T)+t)*V + col].
// ---------------------------------------------------------------------------
__global__ __launch_bounds__(256) void gemm_bt(
    const u16* __restrict__ A, const u16* __restrict__ Bt,
    const float* __restrict__ bias, float* __restrict__ C,
    int M, int N, int K, int lda, int ldb, long long ldc,
    long long sA, long long sB, long long sC,
    int mode, float* __restrict__ rowsum)
{
    __shared__ u16 As[64][40];
    __shared__ u16 Bs[64][40];
    const int bz = blockIdx.z;
    A  += (long long)bz * sA;
    Bt += (long long)bz * sB;
    C  += (long long)bz * sC;
    const int m0 = blockIdx.x * 64, n0 = blockIdx.y * 64;
    const int tid = threadIdx.x, wave = tid >> 6, lane = tid & 63;
    const int wm = (wave >> 1) * 32, wn = (wave & 1) * 32;
    const int srow = tid >> 2, scol = (tid & 3) * 8;
    const int fr = lane & 15, kq = lane >> 4;
    f32x4 acc[2][2];
#pragma unroll
    for (int i = 0; i < 2; ++i)
#pragma unroll
        for (int j = 0; j < 2; ++j) acc[i][j] = (f32x4){0.f, 0.f, 0.f, 0.f};

    for (int k0 = 0; k0 < K; k0 += 32) {
        {
            int gr = m0 + srow, gc = k0 + scol;
            bf16x8 v;
            if (gr < M && gc + 8 <= K) {
                v = *(const bf16x8*)(A + (long long)gr * lda + gc);
            } else {
                short tmp[8];
#pragma unroll
                for (int j = 0; j < 8; ++j)
                    tmp[j] = (gr < M && gc + j < K) ? (short)A[(long long)gr * lda + gc + j] : (short)0;
                v = *(bf16x8*)tmp;
            }
            *(bf16x8*)&As[srow][scol] = v;
        }
        {
            int gr = n0 + srow, gc = k0 + scol;
            bf16x8 v;
            if (gr < N && gc + 8 <= K) {
                v = *(const bf16x8*)(Bt + (long long)gr * ldb + gc);
            } else {
                short tmp[8];
#pragma unroll
                for (int j = 0; j < 8; ++j)
                    tmp[j] = (gr < N && gc + j < K) ? (short)Bt[(long long)gr * ldb + gc + j] : (short)0;
                v = *(bf16x8*)tmp;
            }
            *(bf16x8*)&Bs[srow][scol] = v;
        }
        __syncthreads();
        bf16x8 af[2], bfr[2];
#pragma unroll
        for (int i = 0; i < 2; ++i) af[i]  = *(const bf16x8*)&As[wm + i * 16 + fr][kq * 8];
#pragma unroll
        for (int j = 0; j < 2; ++j) bfr[j] = *(const bf16x8*)&Bs[wn + j * 16 + fr][kq * 8];
#pragma unroll
        for (int i = 0; i < 2; ++i)
#pragma unroll
            for (int j = 0; j < 2; ++j)
                acc[i][j] = __builtin_amdgcn_mfma_f32_16x16x32_bf16(af[i], bfr[j], acc[i][j], 0, 0, 0);
        __syncthreads();
    }

#pragma unroll
    for (int i = 0; i < 2; ++i)
#pragma unroll
        for (int j = 0; j < 2; ++j) {
            int col = n0 + wn + j * 16 + fr;
            float bv = (bias != nullptr && col < N) ? bias[col] : 0.f;
#pragma unroll
            for (int r = 0; r < 4; ++r) {
                int row = m0 + wm + i * 16 + kq * 4 + r;
                bool ok = (row < M) && (col < N);
                float v = acc[i][j][r] + bv;
                if (mode >= 1) { v = ok ? __expf(v) : 0.f; acc[i][j][r] = v; }
                if (ok) {
                    long long coff;
                    if (mode == 2)
                        coff = ((long long)(row % NB) * T + (row / NB)) * (long long)V + col;
                    else
                        coff = (long long)row * ldc + col;
                    C[coff] = v;
                }
            }
        }
    if (mode >= 1) {
#pragma unroll
        for (int i = 0; i < 2; ++i)
#pragma unroll
            for (int r = 0; r < 4; ++r) {
                float s = acc[i][0][r] + acc[i][1][r];
                s += __shfl_xor(s, 1); s += __shfl_xor(s, 2);
                s += __shfl_xor(s, 4); s += __shfl_xor(s, 8);
                if (fr == 0) {
                    int row = m0 + wm + i * 16 + kq * 4 + r;
                    if (row < M) atomicAdd(&rowsum[row], s);
                }
            }
    }
}

// ---------------------------------------------------------------------------
// small utility kernels
// ---------------------------------------------------------------------------
__global__ void cvt_bf16_kernel(const float* __restrict__ src, u16* __restrict__ dst, int n) {
    for (int i = blockIdx.x * blockDim.x + threadIdx.x; i < n; i += gridDim.x * blockDim.x)
        dst[i] = f2bf(src[i]);
}

__global__ void cvt4_kernel(const float* __restrict__ a, const float* __restrict__ b,
                            const float* __restrict__ c, const float* __restrict__ d,
                            u16* __restrict__ da, u16* __restrict__ db,
                            u16* __restrict__ dc, u16* __restrict__ dd, int n) {
    for (int i = blockIdx.x * blockDim.x + threadIdx.x; i < n; i += gridDim.x * blockDim.x) {
        da[i] = f2bf(a[i]); db[i] = f2bf(b[i]); dc[i] = f2bf(c[i]); dd[i] = f2bf(d[i]);
    }
}

// weight prep for the distributed encoder: dst[dir][j][rloc][k], rloc = g*20+c
__global__ void prep_wenc_kernel(const float* __restrict__ whhf, const float* __restrict__ whhb,
                                 u16* __restrict__ dst) {
    int idx = blockIdx.x * 256 + threadIdx.x;
    const int total = 2 * ENBLK * EROWS * EKP;
    if (idx >= total) return;
    int k = idx % EKP; int r = idx / EKP;
    int rloc = r % EROWS; r /= EROWS;
    int j = r % ENBLK; int dir = r / ENBLK;
    u16 v = 0;
    if (k < H && rloc < 3 * ESL) {
        int g = rloc / ESL, c = rloc % ESL;
        const float* W = dir ? whhb : whhf;
        v = f2bf(W[(long long)(g * H + j * ESL + c) * H + k]);
    }
    dst[idx] = v;
}

__global__ void embed_story_kernel(const int* __restrict__ story, const u16* __restrict__ embb,
                                   u16* __restrict__ xb) {
    int row = blockIdx.x;                 // row = s*16 + b
    int s = row >> 4, b = row & 15;
    int tok = story[b * S + s];
    const u16* e = embb + (long long)tok * H;
    u16* d = xb + (long long)row * H;
    for (int k = threadIdx.x; k < H; k += blockDim.x) d[k] = e[k];
}

__global__ void build_decin_kernel(const int* __restrict__ tgt, const int* __restrict__ dom,
                                   const int* __restrict__ sidx, const float* __restrict__ slt,
                                   const u16* __restrict__ embb, u16* __restrict__ decin) {
    int n = blockIdx.x, t = blockIdx.y;
    int b = n & 15, slot = n >> 4;
    u16* d = decin + ((long long)t * NB + n) * H;
    if (t == 0) {
        const float* s1 = slt + (long long)dom[slot] * H;
        const float* s2 = slt + (long long)sidx[slot] * H;
        for (int k = threadIdx.x; k < H; k += blockDim.x) d[k] = f2bf(s1[k] + s2[k]);
    } else {
        int tok = tgt[(b * NSLOT + slot) * T + (t - 1)];
        const u16* e = embb + (long long)tok * H;
        for (int k = threadIdx.x; k < H; k += blockDim.x) d[k] = e[k];
    }
}

// ---------------------------------------------------------------------------
// Distributed encoder recurrence — EXACT round-3 protocol (best measured):
// relaxed agent spin + s_sleep backoff; one acquire fence per wave; packed
// (hi|lo) u32 relaxed agent publish stores; barrier; tid0 RELEASE flag store.
// ---------------------------------------------------------------------------
__global__ __launch_bounds__(256) void enc_rnn2_kernel(
    const u16* __restrict__ wencp,
    const float* __restrict__ bhhf, const float* __restrict__ bhhb,
    const float* __restrict__ gif, const float* __restrict__ gib,
    const int* __restrict__ lens,
    unsigned* __restrict__ hbuf, int* __restrict__ flags,
    float* __restrict__ ysf, float* __restrict__ ysb,
    float* __restrict__ hfo, float* __restrict__ hbo)
{
    const int bid = blockIdx.x;
    const int dir = bid / ENBLK, j = bid % ENBLK;
    const float* bhh = dir ? bhhb : bhhf;
    const float* gi  = dir ? gib  : gif;
    float* ys = dir ? ysb : ysf;
    float* ho = dir ? hbo : hfo;

    __shared__ u16 wlds[EROWS * EKP];      // 53248 B
    __shared__ float ghs[EROWS * 17];      // 4352 B

    const int tid = threadIdx.x, wave = tid >> 6, lane = tid & 63;
    const int fr = lane & 15, kq = lane >> 4;

    const u16* wsrc = wencp + (long long)(dir * ENBLK + j) * EROWS * EKP;
    for (int i = tid * 8; i < EROWS * EKP; i += 256 * 8)
        *(bf16x8*)&wlds[i] = *(const bf16x8*)&wsrc[i];
    for (int i = tid; i < EROWS * 17; i += 256) ghs[i] = 0.f;

    const int p0 = tid, p1 = 256 + tid;
    const bool has1 = (tid < 64);
    const int b0 = p0 / ESL, kl0 = p0 % ESL;
    const int b1 = has1 ? p1 / ESL : 0, kl1 = has1 ? p1 % ESL : 0;
    const int k0 = j * ESL;
    const int len0 = lens[b0];
    const int len1 = has1 ? lens[b1] : 0;
    const float bhr0 = bhh[k0 + kl0], bhz0 = bhh[H + k0 + kl0], bhn0 = bhh[2 * H + k0 + kl0];
    const float bhr1 = has1 ? bhh[k0 + kl1] : 0.f;
    const float bhz1 = has1 ? bhh[H + k0 + kl1] : 0.f;
    const float bhn1 = has1 ? bhh[2 * H + k0 + kl1] : 0.f;
    float h0r = 0.f, h1r = 0.f;

    const int fbase = dir * ENBLK;
    unsigned* hb_d = hbuf + (long long)dir * 2 * B * EKP;
    const u16* arow = &wlds[(wave * 16 + fr) * EKP + kq * 8];
    __syncthreads();

    for (int t = 0; t < S; ++t) {
        const int s = dir ? (S - 1 - t) : t;
        const float* gbase = gi + (long long)s * B * H3;
        float gr0 = gbase[b0 * H3 + k0 + kl0];
        float gz0 = gbase[b0 * H3 + H + k0 + kl0];
        float gn0 = gbase[b0 * H3 + 2 * H + k0 + kl0];
        float gr1 = 0.f, gz1 = 0.f, gn1 = 0.f;
        if (has1) {
            gr1 = gbase[b1 * H3 + k0 + kl1];
            gz1 = gbase[b1 * H3 + H + k0 + kl1];
            gn1 = gbase[b1 * H3 + 2 * H + k0 + kl1];
        }

        f32x4 acc = (f32x4){0.f, 0.f, 0.f, 0.f};
        if (t > 0) {
            // relaxed spin (sc1 load, no cache maintenance) + backoff
            for (;;) {
                int v = 0x7fffffff;
                if (lane < ENBLK)
                    v = __hip_atomic_load(&flags[fbase + lane], __ATOMIC_RELAXED,
                                          __HIP_MEMORY_SCOPE_AGENT);
                if (__all(v >= t)) break;
                __builtin_amdgcn_s_sleep(2);
            }
            // one acquire fence: invalidate stale L2 lines before reading hbuf
            __builtin_amdgcn_fence(__ATOMIC_ACQUIRE, "agent");
            const unsigned* hrow = hb_d + (long long)(t & 1) * B * EKP
                                   + (long long)fr * EKP + kq * 8;
            f32x4 acch = (f32x4){0.f, 0.f, 0.f, 0.f};
            f32x4 accl = (f32x4){0.f, 0.f, 0.f, 0.f};
#pragma unroll
            for (int kk = 0; kk < 13; ++kk) {
                u32x4 a = *(const u32x4*)(hrow + kk * 32);
                u32x4 b = *(const u32x4*)(hrow + kk * 32 + 4);
                union { unsigned u[4]; bf16x8 v; } hi, lo;
                hi.u[0] = __builtin_amdgcn_perm(a[1], a[0], 0x05040100u);
                hi.u[1] = __builtin_amdgcn_perm(a[3], a[2], 0x05040100u);
                hi.u[2] = __builtin_amdgcn_perm(b[1], b[0], 0x05040100u);
                hi.u[3] = __builtin_amdgcn_perm(b[3], b[2], 0x05040100u);
                lo.u[0] = __builtin_amdgcn_perm(a[1], a[0], 0x07060302u);
                lo.u[1] = __builtin_amdgcn_perm(a[3], a[2], 0x07060302u);
                lo.u[2] = __builtin_amdgcn_perm(b[1], b[0], 0x07060302u);
                lo.u[3] = __builtin_amdgcn_perm(b[3], b[2], 0x07060302u);
                bf16x8 av = *(const bf16x8*)(arow + kk * 32);
                acch = __builtin_amdgcn_mfma_f32_16x16x32_bf16(av, hi.v, acch, 0, 0, 0);
                accl = __builtin_amdgcn_mfma_f32_16x16x32_bf16(av, lo.v, accl, 0, 0, 0);
            }
            acc = acch + accl;
        }
#pragma unroll
        for (int r = 0; r < 4; ++r) ghs[(wave * 16 + kq * 4 + r) * 17 + fr] = acc[r];
        __syncthreads();

        unsigned* hpub = hb_d + (long long)((t + 1) & 1) * B * EKP;
        {
            float ghr = ghs[kl0 * 17 + b0];
            float ghz = ghs[(ESL + kl0) * 17 + b0];
            float ghn = ghs[(2 * ESL + kl0) * 17 + b0];
            float rg = sigm(gr0 + ghr + bhr0);
            float zg = sigm(gz0 + ghz + bhz0);
            float ng = tanhf(gn0 + rg * (ghn + bhn0));
            float hn = (1.f - zg) * ng + zg * h0r;
            bool msk = s < len0;
            float y = msk ? hn : 0.f;
            if (msk) h0r = hn;
            ys[((long long)(b0 * S + s)) * H + k0 + kl0] = y;
            u16 hi = f2bf(h0r);
            unsigned packed = (unsigned)hi | ((unsigned)f2bf(h0r - bf2f(hi)) << 16);
            __hip_atomic_store(&hpub[b0 * EKP + k0 + kl0], packed, __ATOMIC_RELAXED,
                               __HIP_MEMORY_SCOPE_AGENT);
        }
        if (has1) {
            float ghr = ghs[kl1 * 17 + b1];
            float ghz = ghs[(ESL + kl1) * 17 + b1];
            float ghn = ghs[(2 * ESL + kl1) * 17 + b1];
            float rg = sigm(gr1 + ghr + bhr1);
            float zg = sigm(gz1 + ghz + bhz1);
            float ng = tanhf(gn1 + rg * (ghn + bhn1));
            float hn = (1.f - zg) * ng + zg * h1r;
            bool msk = s < len1;
            float y = msk ? hn : 0.f;
            if (msk) h1r = hn;
            ys[((long long)(b1 * S + s)) * H + k0 + kl1] = y;
            u16 hi = f2bf(h1r);
            unsigned packed = (unsigned)hi | ((unsigned)f2bf(h1r - bf2f(hi)) << 16);
            __hip_atomic_store(&hpub[b1 * EKP + k0 + kl1], packed, __ATOMIC_RELAXED,
                               __HIP_MEMORY_SCOPE_AGENT);
        }
        // barrier drains every wave's stores (vmcnt0) before the release flag
        __syncthreads();
        if (tid == 0)
            __hip_atomic_store(&flags[fbase + j], t + 1, __ATOMIC_RELEASE,
                               __HIP_MEMORY_SCOPE_AGENT);
    }
    ho[b0 * H + k0 + kl0] = h0r;
    if (has1) ho[b1 * H + k0 + kl1] = h1r;
}

// E = ys_f + ys_b (bf16, [b][s][k]) and ET (bf16, [b][k][s])
__global__ void packE_kernel(const float* __restrict__ ysf, const float* __restrict__ ysb,
                             u16* __restrict__ E, u16* __restrict__ ET) {
    __shared__ u16 tile[32][400];
    const int b = blockIdx.x, s0 = blockIdx.y * 32;
    for (int si = 0; si < 32; ++si) {
        const long long base = ((long long)b * S + s0 + si) * H;
        for (int k = threadIdx.x; k < H; k += blockDim.x) {
            u16 v = f2bf(ysf[base + k] + ysb[base + k]);
            E[base + k] = v;
            tile[si][k] = v;
        }
    }
    __syncthreads();
    for (int idx = threadIdx.x; idx < 32 * H; idx += blockDim.x) {
        int k = idx >> 5, si = idx & 31;
        ET[((long long)b * H + k) * S + s0 + si] = tile[si][k];
    }
}

__global__ void h0_kernel(const float* __restrict__ hf, const float* __restrict__ hb,
                          float* __restrict__ hf32, u16* __restrict__ hnk) {
    int n = blockIdx.x, b = n & 15;
    for (int k = threadIdx.x; k < H; k += blockDim.x) {
        float v = hf[b * H + k] + hb[b * H + k];
        hf32[(long long)n * H + k] = v;
        hnk[(long long)n * H + k] = f2bf(v);
    }
}

// ---------------------------------------------------------------------------
// Fused decoder step: block = batch b (16 blocks, 512 threads, dynamic LDS).
// Writes h_t (bf16) into hall[t] for the batched vocab GEMM; sw/prob per t.
// ---------------------------------------------------------------------------
__global__ __launch_bounds__(512) void fused_step_kernel(
    const float* __restrict__ dgi, const float* __restrict__ dgh,
    float* __restrict__ hf32, u16* __restrict__ hall,
    const u16* __restrict__ decinb,
    const u16* __restrict__ Eb, const u16* __restrict__ ETb,
    const int* __restrict__ lens,
    const float* __restrict__ Wr, const float* __restrict__ br,
    const float* __restrict__ Wg, const float* __restrict__ bg,
    float* __restrict__ probfT, float* __restrict__ swvT,
    float* __restrict__ gout, int t)
{
    extern __shared__ char smem[];
    u16*   hls = (u16*)smem;                                   // [32][HP2]
    float* scs = (float*)(smem + 32 * HP2 * 2);                // [32][SCP]
    u16*   pls = (u16*)(smem + 32 * HP2 * 2 + 32 * SCP * 4);   // [32][PP]
    float* cxs = (float*)(smem + 32 * HP2 * 2 + 32 * SCP * 4 + 32 * PP * 2); // [32][CXP]

    const int b = blockIdx.x;
    const int tid = threadIdx.x, wave = tid >> 6, lane = tid & 63;
    const int fr = lane & 15, kq = lane >> 4;
    const int len = lens[b];

    for (int i = tid; i < 32 * (HP2 - H); i += 512) {
        int r = i / (HP2 - H), c = H + i % (HP2 - H);
        hls[r * HP2 + c] = 0;
    }
    for (int i = tid; i < 2 * HP2; i += 512) hls[30 * HP2 + i] = 0;
    for (int i = tid; i < 2 * PP; i += 512) pls[30 * PP + i] = 0;

    // P0: GRU cell for the 30 slots of this batch
    for (int i = tid; i < 30 * H; i += 512) {
        int slot = i / H, k = i % H;
        int n = slot * 16 + b;
        const float* gi = dgi + ((long long)t * NB + n) * H3;
        const float* gh = dgh + (long long)n * H3;
        float r  = sigm(gi[k] + gh[k]);
        float z  = sigm(gi[H + k] + gh[H + k]);
        float nn = tanhf(gi[2 * H + k] + r * gh[2 * H + k]);
        float h  = hf32[(long long)n * H + k];
        float hn = (1.f - z) * nn + z * h;
        hf32[(long long)n * H + k] = hn;
        u16 hb = f2bf(hn);
        hall[((long long)t * NB + n) * H + k] = hb;
        hls[slot * HP2 + k] = hb;
    }
    __syncthreads();

    // P1: scores[slot][s] = h . E[b][s]   (M=32, N=256, K=400)
    {
        const int nt0 = wave * 2;
        f32x4 acc[2][2];
#pragma unroll
        for (int i = 0; i < 2; ++i)
#pragma unroll
            for (int jj = 0; jj < 2; ++jj) acc[i][jj] = (f32x4){0.f, 0.f, 0.f, 0.f};
        const u16* br0 = Eb + ((long long)b * S + nt0 * 16 + fr) * H + kq * 8;
        const u16* br1 = Eb + ((long long)b * S + (nt0 + 1) * 16 + fr) * H + kq * 8;
        const u16* ar0 = hls + fr * HP2 + kq * 8;
        const u16* ar1 = hls + (16 + fr) * HP2 + kq * 8;
#pragma unroll
        for (int kk = 0; kk < 13; ++kk) {
            bf16x8 av0 = *(const bf16x8*)(ar0 + kk * 32);
            bf16x8 av1 = *(const bf16x8*)(ar1 + kk * 32);
            bf16x8 bv0, bv1;
            if (kk == 12 && kq >= 2) {
                bv0 = (bf16x8){0,0,0,0,0,0,0,0}; bv1 = bv0;
            } else {
                bv0 = *(const bf16x8*)(br0 + kk * 32);
                bv1 = *(const bf16x8*)(br1 + kk * 32);
            }
            acc[0][0] = __builtin_amdgcn_mfma_f32_16x16x32_bf16(av0, bv0, acc[0][0], 0, 0, 0);
            acc[1][0] = __builtin_amdgcn_mfma_f32_16x16x32_bf16(av1, bv0, acc[1][0], 0, 0, 0);
            acc[0][1] = __builtin_amdgcn_mfma_f32_16x16x32_bf16(av0, bv1, acc[0][1], 0, 0, 0);
            acc[1][1] = __builtin_amdgcn_mfma_f32_16x16x32_bf16(av1, bv1, acc[1][1], 0, 0, 0);
        }
#pragma unroll
        for (int i = 0; i < 2; ++i)
#pragma unroll
            for (int jj = 0; jj < 2; ++jj)
#pragma unroll
                for (int r = 0; r < 4; ++r)
                    scs[(i * 16 + kq * 4 + r) * SCP + (nt0 + jj) * 16 + fr] = acc[i][jj][r];
    }
    __syncthreads();

    // P2: softmax rows
    for (int i = 0; i < 4; ++i) {
        int row = wave * 4 + i;
        if (row >= 30) break;
        int n = row * 16 + b;
        float v[4];
        float mx = -3.0e38f;
#pragma unroll
        for (int q = 0; q < 4; ++q) {
            int s = lane + 64 * q;
            float x = (s < len) ? scs[row * SCP + s] : -3.0e38f;
            v[q] = x; mx = fmaxf(mx, x);
        }
        mx = fmaxf(mx, __shfl_xor(mx, 1));  mx = fmaxf(mx, __shfl_xor(mx, 2));
        mx = fmaxf(mx, __shfl_xor(mx, 4));  mx = fmaxf(mx, __shfl_xor(mx, 8));
        mx = fmaxf(mx, __shfl_xor(mx, 16)); mx = fmaxf(mx, __shfl_xor(mx, 32));
        float sum = 0.f;
#pragma unroll
        for (int q = 0; q < 4; ++q) {
            int s = lane + 64 * q;
            float e = (s < len) ? __expf(v[q] - mx) : 0.f;
            v[q] = e; sum += e;
        }
        sum += __shfl_xor(sum, 1);  sum += __shfl_xor(sum, 2);
        sum += __shfl_xor(sum, 4);  sum += __shfl_xor(sum, 8);
        sum += __shfl_xor(sum, 16); sum += __shfl_xor(sum, 32);
        float inv = 1.f / sum;
#pragma unroll
        for (int q = 0; q < 4; ++q) {
            int s = lane + 64 * q;
            float pr = v[q] * inv;
            pls[row * PP + s] = f2bf(pr);
            probfT[((long long)(t * NB + n)) * S + s] = pr;
        }
    }
    __syncthreads();

    // P3: ctx[slot][k] = sum_s prob[slot][s] * ET[b][k][s]
    for (int nt = wave; nt < 25; nt += 8) {
        f32x4 acc0 = (f32x4){0.f,0.f,0.f,0.f}, acc1 = (f32x4){0.f,0.f,0.f,0.f};
        const u16* brow = ETb + ((long long)b * H + nt * 16 + fr) * S + kq * 8;
        const u16* ar0 = pls + fr * PP + kq * 8;
        const u16* ar1 = pls + (16 + fr) * PP + kq * 8;
#pragma unroll
        for (int kk = 0; kk < 8; ++kk) {
            bf16x8 bv  = *(const bf16x8*)(brow + kk * 32);
            bf16x8 av0 = *(const bf16x8*)(ar0 + kk * 32);
            bf16x8 av1 = *(const bf16x8*)(ar1 + kk * 32);
            acc0 = __builtin_amdgcn_mfma_f32_16x16x32_bf16(av0, bv, acc0, 0, 0, 0);
            acc1 = __builtin_amdgcn_mfma_f32_16x16x32_bf16(av1, bv, acc1, 0, 0, 0);
        }
#pragma unroll
        for (int r = 0; r < 4; ++r) {
            cxs[(kq * 4 + r) * CXP + nt * 16 + fr] = acc0[r];
            cxs[(16 + kq * 4 + r) * CXP + nt * 16 + fr] = acc1[r];
        }
    }
    __syncthreads();

    // P4: p_gen switch (+ gate at t==0)
    for (int i = 0; i < 4; ++i) {
        int slot = wave + 8 * i;
        if (slot >= 30) break;
        int n = slot * 16 + b;
        const u16* xrow = decinb + ((long long)t * NB + n) * H;
        float p = 0.f;
        for (int k = lane; k < H; k += 64)
            p += bf2f(hls[slot * HP2 + k]) * Wr[k]
               + cxs[slot * CXP + k] * Wr[H + k]
               + bf2f(xrow[k]) * Wr[2 * H + k];
        p += __shfl_xor(p, 1);  p += __shfl_xor(p, 2);
        p += __shfl_xor(p, 4);  p += __shfl_xor(p, 8);
        p += __shfl_xor(p, 16); p += __shfl_xor(p, 32);
        if (lane == 0) swvT[t * NB + n] = sigm(p + br[0]);
        if (t == 0) {
            for (int g = 0; g < G; ++g) {
                float q = 0.f;
                for (int k = lane; k < H; k += 64)
                    q += cxs[slot * CXP + k] * Wg[g * H + k];
                q += __shfl_xor(q, 1);  q += __shfl_xor(q, 2);
                q += __shfl_xor(q, 4);  q += __shfl_xor(q, 8);
                q += __shfl_xor(q, 16); q += __shfl_xor(q, 32);
                if (lane == 0) gout[(long long)n * G + g] = q + bg[g];
            }
        }
    }
}

// scale all t at once: out[n][t][:] *= sw[t][n] / rowsum[t*NB+n]
__global__ void scale_all_kernel(float* __restrict__ out, const float* __restrict__ swvT,
                                 const float* __restrict__ rowsumT) {
    const int n = blockIdx.x;
    const int col = blockIdx.y * 256 + threadIdx.x;
    if (col >= V) return;
#pragma unroll
    for (int t = 0; t < T; ++t) {
        float f = swvT[t * NB + n] / rowsumT[t * NB + n];
        out[((long long)n * T + t) * V + col] *= f;
    }
}

__global__ void scatter_all_kernel(float* __restrict__ out, const int* __restrict__ story,
                                   const int* __restrict__ lens, const float* __restrict__ swvT,
                                   const float* __restrict__ probfT) {
    const int n = blockIdx.x, t = blockIdx.y, b = n & 15, s = threadIdx.x;
    if (s < lens[b]) {
        int tok = story[b * S + s];
        atomicAdd(out + ((long long)n * T + t) * V + tok,
                  (1.f - swvT[t * NB + n]) * probfT[((long long)(t * NB + n)) * S + s]);
    }
}

// ---------------------------------------------------------------------------
extern "C" void kernel_launch(void* const* d_in, const int* in_sizes, int n_in,
                              void* d_out, int out_size, void* d_ws, size_t ws_size,
                              hipStream_t stream) {
    const int*   story = (const int*)d_in[0];
    const int*   lens  = (const int*)d_in[1];
    const int*   tgt   = (const int*)d_in[2];
    const int*   dom   = (const int*)d_in[3];
    const int*   sidx  = (const int*)d_in[4];
    const float* emb   = (const float*)d_in[5];
    const float* wihf  = (const float*)d_in[6];
    const float* whhf  = (const float*)d_in[7];
    const float* bihf  = (const float*)d_in[8];
    const float* bhhf  = (const float*)d_in[9];
    const float* wihb  = (const float*)d_in[10];
    const float* whhb  = (const float*)d_in[11];
    const float* bihb  = (const float*)d_in[12];
    const float* bhhb  = (const float*)d_in[13];
    const float* dwih  = (const float*)d_in[14];
    const float* dwhh  = (const float*)d_in[15];
    const float* dbih  = (const float*)d_in[16];
    const float* dbhh  = (const float*)d_in[17];
    const float* Wr    = (const float*)d_in[18];
    const float* br    = (const float*)d_in[19];
    const float* Wg    = (const float*)d_in[20];
    const float* bg    = (const float*)d_in[21];
    const float* slt   = (const float*)d_in[22];
    float* out = (float*)d_out;

    char* wsb = (char*)d_ws;
    size_t off = 0;
    auto alloc = [&](size_t bytes) -> char* {
        char* p = wsb + off;
        off += (bytes + 255) & ~(size_t)255;
        return p;
    };
    u16*   embb   = (u16*)alloc((size_t)V * H * 2);
    u16*   wihfb  = (u16*)alloc((size_t)H3 * H * 2);
    u16*   wihbb  = (u16*)alloc((size_t)H3 * H * 2);
    u16*   dwihb  = (u16*)alloc((size_t)H3 * H * 2);
    u16*   dwhhb  = (u16*)alloc((size_t)H3 * H * 2);
    u16*   wencp  = (u16*)alloc((size_t)2 * ENBLK * EROWS * EKP * 2);
    unsigned* hbuf = (unsigned*)alloc((size_t)2 * 2 * B * EKP * 4);
    int*   flags  = (int*)alloc((size_t)2 * ENBLK * 4);
    u16*   xb     = (u16*)alloc((size_t)S * B * H * 2);
    u16*   decinb = (u16*)alloc((size_t)T * NB * H * 2);
    float* gif    = (float*)alloc((size_t)S * B * H3 * 4);
    float* gib    = (float*)alloc((size_t)S * B * H3 * 4);
    float* dgi    = (float*)alloc((size_t)T * NB * H3 * 4);
    float* ysf    = (float*)alloc((size_t)B * S * H * 4);
    float* ysb    = (float*)alloc((size_t)B * S * H * 4);
    float* hfv    = (float*)alloc((size_t)B * H * 4);
    float* hbv    = (float*)alloc((size_t)B * H * 4);
    u16*   Eb     = (u16*)alloc((size_t)B * S * H * 2);
    u16*   ETb    = (u16*)alloc((size_t)B * H * S * 2);
    float* hf32   = (float*)alloc((size_t)NB * H * 4);
    u16*   hnk    = (u16*)alloc((size_t)NB * H * 2);
    u16*   hall   = (u16*)alloc((size_t)T * NB * H * 2);
    float* dgh    = (float*)alloc((size_t)NB * H3 * 4);
    float* probfT = (float*)alloc((size_t)T * NB * S * 4);
    float* swvT   = (float*)alloc((size_t)T * NB * 4);
    float* rowsumT = (float*)alloc((size_t)T * NB * 4);
    (void)ws_size; (void)in_sizes; (void)n_in; (void)out_size;

    auto launch_gemm = [&](const u16* A, const u16* Bt, const float* bias, float* C,
                           int M, int N, int K, int lda, int ldb, long long ldc,
                           long long sA, long long sB, long long sC, int nb,
                           int mode, float* rs) {
        dim3 g((M + 63) / 64, (N + 63) / 64, nb);
        gemm_bt<<<g, 256, 0, stream>>>(A, Bt, bias, C, M, N, K, lda, ldb, ldc,
                                       sA, sB, sC, mode, rs);
    };

    hipFuncSetAttribute((const void*)fused_step_kernel,
                        hipFuncAttributeMaxDynamicSharedMemorySize, FUSED_LDS);

    // ---- setup: casts, embeddings, input-side GEMMs -----------------------
    cvt_bf16_kernel<<<2048, 256, 0, stream>>>(emb, embb, V * H);
    cvt4_kernel<<<1024, 256, 0, stream>>>(wihf, wihb, dwih, dwhh,
                                          wihfb, wihbb, dwihb, dwhhb, H3 * H);
    {
        const int total = 2 * ENBLK * EROWS * EKP;
        prep_wenc_kernel<<<(total + 255) / 256, 256, 0, stream>>>(whhf, whhb, wencp);
    }
    embed_story_kernel<<<S * B, 256, 0, stream>>>(story, embb, xb);
    { dim3 g(NB, T); build_decin_kernel<<<g, 256, 0, stream>>>(tgt, dom, sidx, slt, embb, decinb); }

    launch_gemm(xb, wihfb, bihf, gif, S * B, H3, H, H, H, H3, 0, 0, 0, 1, 0, nullptr);
    launch_gemm(xb, wihbb, bihb, gib, S * B, H3, H, H, H, H3, 0, 0, 0, 1, 0, nullptr);
    launch_gemm(decinb, dwihb, dbih, dgi, T * NB, H3, H, H, H, H3, 0, 0, 0, 1, 0, nullptr);

    // ---- encoder recurrence (R3 protocol, best measured) ------------------
    hipMemsetAsync(flags, 0, (size_t)2 * ENBLK * 4, stream);
    hipMemsetAsync(hbuf, 0, (size_t)2 * 2 * B * EKP * 4, stream);
    hipMemsetAsync(rowsumT, 0, (size_t)T * NB * 4, stream);
    enc_rnn2_kernel<<<2 * ENBLK, 256, 0, stream>>>(wencp, bhhf, bhhb, gif, gib, lens,
                                                   hbuf, flags, ysf, ysb, hfv, hbv);
    { dim3 g(B, S / 32); packE_kernel<<<g, 256, 0, stream>>>(ysf, ysb, Eb, ETb); }
    h0_kernel<<<NB, 256, 0, stream>>>(hfv, hbv, hf32, hnk);

    // ---- decoder: sequential chain (2 launches/step) ----------------------
    for (int t = 0; t < T; ++t) {
        const u16* hprev = (t == 0) ? hnk : hall + (size_t)(t - 1) * NB * H;
        launch_gemm(hprev, dwhhb, dbhh, dgh, NB, H3, H, H, H, H3, 0, 0, 0, 1, 0, nullptr);
        fused_step_kernel<<<16, 512, FUSED_LDS, stream>>>(
            dgi, dgh, hf32, hall, decinb, Eb, ETb, lens, Wr, br, Wg, bg,
            probfT, swvT, out + (size_t)NB * T * V, t);
    }

    // ---- batched vocab projection: one GEMM over all (t, n) rows ----------
    launch_gemm(hall, embb, nullptr, out, T * NB, V, H, H, H, V,
                0, 0, 0, 1, 2, rowsumT);
    { dim3 g(NB, (V + 255) / 256); scale_all_kernel<<<g, 256, 0, stream>>>(out, swvT, rowsumT); }
    { dim3 g(NB, T); scatter_all_kernel<<<g, 256, 0, stream>>>(out, story, lens, swvT, probfT); }
}

// Round 7
// 2613.656 us; speedup vs baseline: 2.0366x; 1.1764x over previous
//
#include <hip/hip_runtime.h>
#include <hip/hip_bf16.h>

typedef unsigned short u16;
typedef __attribute__((ext_vector_type(8))) short bf16x8;
typedef __attribute__((ext_vector_type(4))) float f32x4;
typedef __attribute__((ext_vector_type(4))) unsigned u32x4;

static constexpr int V = 20000, H = 400, B = 16, S = 256, NSLOT = 30, T = 10, G = 3;
static constexpr int H3 = 3 * H;           // 1200
static constexpr int NB = NSLOT * B;       // 480
// encoder partition
static constexpr int ENBLK = 20;           // blocks per direction
static constexpr int ESL   = 20;           // h components per block (400/20)
static constexpr int EROWS = 64;           // padded weight rows per block
static constexpr int EKP   = 416;          // padded K
// fused decoder LDS strides
static constexpr int HP2 = 424;            // h_lds row stride (u16)
static constexpr int SCP = 260;            // scores row stride (f32)
static constexpr int PP  = 264;            // prob row stride (u16)
static constexpr int CXP = 404;            // ctx row stride (f32)
static constexpr int FUSED_LDS = 32*HP2*2 + 32*SCP*4 + 32*PP*2 + 32*CXP*4; // 129024

__device__ __forceinline__ float bf2f(u16 v) {
    union { unsigned u; float f; } x; x.u = ((unsigned)v) << 16; return x.f;
}
__device__ __forceinline__ u16 f2bf(float f) {
    union { float f; unsigned u; } x; x.f = f;
    unsigned r = x.u + 0x7fffu + ((x.u >> 16) & 1u);   // round-to-nearest-even
    return (u16)(r >> 16);
}
__device__ __forceinline__ float sigm(float v) { return 1.f / (1.f + __expf(-v)); }

// ---------------------------------------------------------------------------
// Generic batched GEMM: C[m][n] = sum_k A[m][k] * Bt[n][k]  (+bias[n])
// mode 0: plain (+bias). mode 1: C=exp(acc)+rowsum, ldc layout.
// mode 2: C=exp(acc)+rowsum, vocab layout: row=t*NB+n -> C[((n*T)+t)*V + col].
// ---------------------------------------------------------------------------
__global__ __launch_bounds__(256) void gemm_bt(
    const u16* __restrict__ A, const u16* __restrict__ Bt,
    const float* __restrict__ bias, float* __restrict__ C,
    int M, int N, int K, int lda, int ldb, long long ldc,
    long long sA, long long sB, long long sC,
    int mode, float* __restrict__ rowsum)
{
    __shared__ u16 As[64][40];
    __shared__ u16 Bs[64][40];
    const int bz = blockIdx.z;
    A  += (long long)bz * sA;
    Bt += (long long)bz * sB;
    C  += (long long)bz * sC;
    const int m0 = blockIdx.x * 64, n0 = blockIdx.y * 64;
    const int tid = threadIdx.x, wave = tid >> 6, lane = tid & 63;
    const int wm = (wave >> 1) * 32, wn = (wave & 1) * 32;
    const int srow = tid >> 2, scol = (tid & 3) * 8;
    const int fr = lane & 15, kq = lane >> 4;
    f32x4 acc[2][2];
#pragma unroll
    for (int i = 0; i < 2; ++i)
#pragma unroll
        for (int j = 0; j < 2; ++j) acc[i][j] = (f32x4){0.f, 0.f, 0.f, 0.f};

    for (int k0 = 0; k0 < K; k0 += 32) {
        {
            int gr = m0 + srow, gc = k0 + scol;
            bf16x8 v;
            if (gr < M && gc + 8 <= K) {
                v = *(const bf16x8*)(A + (long long)gr * lda + gc);
            } else {
                short tmp[8];
#pragma unroll
                for (int j = 0; j < 8; ++j)
                    tmp[j] = (gr < M && gc + j < K) ? (short)A[(long long)gr * lda + gc + j] : (short)0;
                v = *(bf16x8*)tmp;
            }
            *(bf16x8*)&As[srow][scol] = v;
        }
        {
            int gr = n0 + srow, gc = k0 + scol;
            bf16x8 v;
            if (gr < N && gc + 8 <= K) {
                v = *(const bf16x8*)(Bt + (long long)gr * ldb + gc);
            } else {
                short tmp[8];
#pragma unroll
                for (int j = 0; j < 8; ++j)
                    tmp[j] = (gr < N && gc + j < K) ? (short)Bt[(long long)gr * ldb + gc + j] : (short)0;
                v = *(bf16x8*)tmp;
            }
            *(bf16x8*)&Bs[srow][scol] = v;
        }
        __syncthreads();
        bf16x8 af[2], bfr[2];
#pragma unroll
        for (int i = 0; i < 2; ++i) af[i]  = *(const bf16x8*)&As[wm + i * 16 + fr][kq * 8];
#pragma unroll
        for (int j = 0; j < 2; ++j) bfr[j] = *(const bf16x8*)&Bs[wn + j * 16 + fr][kq * 8];
#pragma unroll
        for (int i = 0; i < 2; ++i)
#pragma unroll
            for (int j = 0; j < 2; ++j)
                acc[i][j] = __builtin_amdgcn_mfma_f32_16x16x32_bf16(af[i], bfr[j], acc[i][j], 0, 0, 0);
        __syncthreads();
    }

#pragma unroll
    for (int i = 0; i < 2; ++i)
#pragma unroll
        for (int j = 0; j < 2; ++j) {
            int col = n0 + wn + j * 16 + fr;
            float bv = (bias != nullptr && col < N) ? bias[col] : 0.f;
#pragma unroll
            for (int r = 0; r < 4; ++r) {
                int row = m0 + wm + i * 16 + kq * 4 + r;
                bool ok = (row < M) && (col < N);
                float v = acc[i][j][r] + bv;
                if (mode >= 1) { v = ok ? __expf(v) : 0.f; acc[i][j][r] = v; }
                if (ok) {
                    long long coff;
                    if (mode == 2)
                        coff = ((long long)(row % NB) * T + (row / NB)) * (long long)V + col;
                    else
                        coff = (long long)row * ldc + col;
                    C[coff] = v;
                }
            }
        }
    if (mode >= 1) {
#pragma unroll
        for (int i = 0; i < 2; ++i)
#pragma unroll
            for (int r = 0; r < 4; ++r) {
                float s = acc[i][0][r] + acc[i][1][r];
                s += __shfl_xor(s, 1); s += __shfl_xor(s, 2);
                s += __shfl_xor(s, 4); s += __shfl_xor(s, 8);
                if (fr == 0) {
                    int row = m0 + wm + i * 16 + kq * 4 + r;
                    if (row < M) atomicAdd(&rowsum[row], s);
                }
            }
    }
}

// ---------------------------------------------------------------------------
// small utility kernels
// ---------------------------------------------------------------------------
__global__ void cvt_bf16_kernel(const float* __restrict__ src, u16* __restrict__ dst, int n) {
    for (int i = blockIdx.x * blockDim.x + threadIdx.x; i < n; i += gridDim.x * blockDim.x)
        dst[i] = f2bf(src[i]);
}

__global__ void cvt4_kernel(const float* __restrict__ a, const float* __restrict__ b,
                            const float* __restrict__ c, const float* __restrict__ d,
                            u16* __restrict__ da, u16* __restrict__ db,
                            u16* __restrict__ dc, u16* __restrict__ dd, int n) {
    for (int i = blockIdx.x * blockDim.x + threadIdx.x; i < n; i += gridDim.x * blockDim.x) {
        da[i] = f2bf(a[i]); db[i] = f2bf(b[i]); dc[i] = f2bf(c[i]); dd[i] = f2bf(d[i]);
    }
}

// weight prep for the distributed encoder: dst[dir][j][rloc][k], rloc = g*20+c
__global__ void prep_wenc_kernel(const float* __restrict__ whhf, const float* __restrict__ whhb,
                                 u16* __restrict__ dst) {
    int idx = blockIdx.x * 256 + threadIdx.x;
    const int total = 2 * ENBLK * EROWS * EKP;
    if (idx >= total) return;
    int k = idx % EKP; int r = idx / EKP;
    int rloc = r % EROWS; r /= EROWS;
    int j = r % ENBLK; int dir = r / ENBLK;
    u16 v = 0;
    if (k < H && rloc < 3 * ESL) {
        int g = rloc / ESL, c = rloc % ESL;
        const float* W = dir ? whhb : whhf;
        v = f2bf(W[(long long)(g * H + j * ESL + c) * H + k]);
    }
    dst[idx] = v;
}

__global__ void embed_story_kernel(const int* __restrict__ story, const u16* __restrict__ embb,
                                   u16* __restrict__ xb) {
    int row = blockIdx.x;                 // row = s*16 + b
    int s = row >> 4, b = row & 15;
    int tok = story[b * S + s];
    const u16* e = embb + (long long)tok * H;
    u16* d = xb + (long long)row * H;
    for (int k = threadIdx.x; k < H; k += blockDim.x) d[k] = e[k];
}

__global__ void build_decin_kernel(const int* __restrict__ tgt, const int* __restrict__ dom,
                                   const int* __restrict__ sidx, const float* __restrict__ slt,
                                   const u16* __restrict__ embb, u16* __restrict__ decin) {
    int n = blockIdx.x, t = blockIdx.y;
    int b = n & 15, slot = n >> 4;
    u16* d = decin + ((long long)t * NB + n) * H;
    if (t == 0) {
        const float* s1 = slt + (long long)dom[slot] * H;
        const float* s2 = slt + (long long)sidx[slot] * H;
        for (int k = threadIdx.x; k < H; k += blockDim.x) d[k] = f2bf(s1[k] + s2[k]);
    } else {
        int tok = tgt[(b * NSLOT + slot) * T + (t - 1)];
        const u16* e = embb + (long long)tok * H;
        for (int k = threadIdx.x; k < H; k += blockDim.x) d[k] = e[k];
    }
}

// ---------------------------------------------------------------------------
// Distributed encoder recurrence — protocol v5 (R6 with relaxed flag):
// relaxed agent spin + s_sleep backoff; one acquire fence per wave (reader);
// packed (hi|lo) u32 relaxed agent write-through publish; __syncthreads
// (vmcnt0 drain -> all publishes at L3); tid0 RELAXED flag store (NO release
// -> no per-step buffer_wbl2 L2 writeback scan on the critical path).
// ---------------------------------------------------------------------------
__global__ __launch_bounds__(256) void enc_rnn2_kernel(
    const u16* __restrict__ wencp,
    const float* __restrict__ bhhf, const float* __restrict__ bhhb,
    const float* __restrict__ gif, const float* __restrict__ gib,
    const int* __restrict__ lens,
    unsigned* __restrict__ hbuf, int* __restrict__ flags,
    float* __restrict__ ysf, float* __restrict__ ysb,
    float* __restrict__ hfo, float* __restrict__ hbo)
{
    const int bid = blockIdx.x;
    const int dir = bid / ENBLK, j = bid % ENBLK;
    const float* bhh = dir ? bhhb : bhhf;
    const float* gi  = dir ? gib  : gif;
    float* ys = dir ? ysb : ysf;
    float* ho = dir ? hbo : hfo;

    __shared__ u16 wlds[EROWS * EKP];      // 53248 B
    __shared__ float ghs[EROWS * 17];      // 4352 B

    const int tid = threadIdx.x, wave = tid >> 6, lane = tid & 63;
    const int fr = lane & 15, kq = lane >> 4;

    const u16* wsrc = wencp + (long long)(dir * ENBLK + j) * EROWS * EKP;
    for (int i = tid * 8; i < EROWS * EKP; i += 256 * 8)
        *(bf16x8*)&wlds[i] = *(const bf16x8*)&wsrc[i];
    for (int i = tid; i < EROWS * 17; i += 256) ghs[i] = 0.f;

    const int p0 = tid, p1 = 256 + tid;
    const bool has1 = (tid < 64);
    const int b0 = p0 / ESL, kl0 = p0 % ESL;
    const int b1 = has1 ? p1 / ESL : 0, kl1 = has1 ? p1 % ESL : 0;
    const int k0 = j * ESL;
    const int len0 = lens[b0];
    const int len1 = has1 ? lens[b1] : 0;
    const float bhr0 = bhh[k0 + kl0], bhz0 = bhh[H + k0 + kl0], bhn0 = bhh[2 * H + k0 + kl0];
    const float bhr1 = has1 ? bhh[k0 + kl1] : 0.f;
    const float bhz1 = has1 ? bhh[H + k0 + kl1] : 0.f;
    const float bhn1 = has1 ? bhh[2 * H + k0 + kl1] : 0.f;
    float h0r = 0.f, h1r = 0.f;

    const int fbase = dir * ENBLK;
    unsigned* hb_d = hbuf + (long long)dir * 2 * B * EKP;
    const u16* arow = &wlds[(wave * 16 + fr) * EKP + kq * 8];
    __syncthreads();

    for (int t = 0; t < S; ++t) {
        const int s = dir ? (S - 1 - t) : t;
        const float* gbase = gi + (long long)s * B * H3;
        float gr0 = gbase[b0 * H3 + k0 + kl0];
        float gz0 = gbase[b0 * H3 + H + k0 + kl0];
        float gn0 = gbase[b0 * H3 + 2 * H + k0 + kl0];
        float gr1 = 0.f, gz1 = 0.f, gn1 = 0.f;
        if (has1) {
            gr1 = gbase[b1 * H3 + k0 + kl1];
            gz1 = gbase[b1 * H3 + H + k0 + kl1];
            gn1 = gbase[b1 * H3 + 2 * H + k0 + kl1];
        }

        f32x4 acc = (f32x4){0.f, 0.f, 0.f, 0.f};
        if (t > 0) {
            // relaxed spin (sc1 load, no cache maintenance) + backoff
            for (;;) {
                int v = 0x7fffffff;
                if (lane < ENBLK)
                    v = __hip_atomic_load(&flags[fbase + lane], __ATOMIC_RELAXED,
                                          __HIP_MEMORY_SCOPE_AGENT);
                if (__all(v >= t)) break;
                __builtin_amdgcn_s_sleep(2);
            }
            // one acquire fence: invalidate stale L2 lines before reading hbuf
            __builtin_amdgcn_fence(__ATOMIC_ACQUIRE, "agent");
            const unsigned* hrow = hb_d + (long long)(t & 1) * B * EKP
                                   + (long long)fr * EKP + kq * 8;
            f32x4 acch = (f32x4){0.f, 0.f, 0.f, 0.f};
            f32x4 accl = (f32x4){0.f, 0.f, 0.f, 0.f};
#pragma unroll
            for (int kk = 0; kk < 13; ++kk) {
                u32x4 a = *(const u32x4*)(hrow + kk * 32);
                u32x4 b = *(const u32x4*)(hrow + kk * 32 + 4);
                union { unsigned u[4]; bf16x8 v; } hi, lo;
                hi.u[0] = __builtin_amdgcn_perm(a[1], a[0], 0x05040100u);
                hi.u[1] = __builtin_amdgcn_perm(a[3], a[2], 0x05040100u);
                hi.u[2] = __builtin_amdgcn_perm(b[1], b[0], 0x05040100u);
                hi.u[3] = __builtin_amdgcn_perm(b[3], b[2], 0x05040100u);
                lo.u[0] = __builtin_amdgcn_perm(a[1], a[0], 0x07060302u);
                lo.u[1] = __builtin_amdgcn_perm(a[3], a[2], 0x07060302u);
                lo.u[2] = __builtin_amdgcn_perm(b[1], b[0], 0x07060302u);
                lo.u[3] = __builtin_amdgcn_perm(b[3], b[2], 0x07060302u);
                bf16x8 av = *(const bf16x8*)(arow + kk * 32);
                acch = __builtin_amdgcn_mfma_f32_16x16x32_bf16(av, hi.v, acch, 0, 0, 0);
                accl = __builtin_amdgcn_mfma_f32_16x16x32_bf16(av, lo.v, accl, 0, 0, 0);
            }
            acc = acch + accl;
        }
#pragma unroll
        for (int r = 0; r < 4; ++r) ghs[(wave * 16 + kq * 4 + r) * 17 + fr] = acc[r];
        __syncthreads();

        unsigned* hpub = hb_d + (long long)((t + 1) & 1) * B * EKP;
        {
            float ghr = ghs[kl0 * 17 + b0];
            float ghz = ghs[(ESL + kl0) * 17 + b0];
            float ghn = ghs[(2 * ESL + kl0) * 17 + b0];
            float rg = sigm(gr0 + ghr + bhr0);
            float zg = sigm(gz0 + ghz + bhz0);
            float ng = tanhf(gn0 + rg * (ghn + bhn0));
            float hn = (1.f - zg) * ng + zg * h0r;
            bool msk = s < len0;
            float y = msk ? hn : 0.f;
            if (msk) h0r = hn;
            ys[((long long)(b0 * S + s)) * H + k0 + kl0] = y;
            u16 hi = f2bf(h0r);
            unsigned packed = (unsigned)hi | ((unsigned)f2bf(h0r - bf2f(hi)) << 16);
            __hip_atomic_store(&hpub[b0 * EKP + k0 + kl0], packed, __ATOMIC_RELAXED,
                               __HIP_MEMORY_SCOPE_AGENT);
        }
        if (has1) {
            float ghr = ghs[kl1 * 17 + b1];
            float ghz = ghs[(ESL + kl1) * 17 + b1];
            float ghn = ghs[(2 * ESL + kl1) * 17 + b1];
            float rg = sigm(gr1 + ghr + bhr1);
            float zg = sigm(gz1 + ghz + bhz1);
            float ng = tanhf(gn1 + rg * (ghn + bhn1));
            float hn = (1.f - zg) * ng + zg * h1r;
            bool msk = s < len1;
            float y = msk ? hn : 0.f;
            if (msk) h1r = hn;
            ys[((long long)(b1 * S + s)) * H + k0 + kl1] = y;
            u16 hi = f2bf(h1r);
            unsigned packed = (unsigned)hi | ((unsigned)f2bf(h1r - bf2f(hi)) << 16);
            __hip_atomic_store(&hpub[b1 * EKP + k0 + kl1], packed, __ATOMIC_RELAXED,
                               __HIP_MEMORY_SCOPE_AGENT);
        }
        // barrier drains every wave's stores (vmcnt0): all write-through
        // publishes are at the coherence point before the flag goes up.
        __syncthreads();
        if (tid == 0)
            __hip_atomic_store(&flags[fbase + j], t + 1, __ATOMIC_RELAXED,
                               __HIP_MEMORY_SCOPE_AGENT);
    }
    ho[b0 * H + k0 + kl0] = h0r;
    if (has1) ho[b1 * H + k0 + kl1] = h1r;
}

// E = ys_f + ys_b (bf16, [b][s][k]) and ET (bf16, [b][k][s])
__global__ void packE_kernel(const float* __restrict__ ysf, const float* __restrict__ ysb,
                             u16* __restrict__ E, u16* __restrict__ ET) {
    __shared__ u16 tile[32][400];
    const int b = blockIdx.x, s0 = blockIdx.y * 32;
    for (int si = 0; si < 32; ++si) {
        const long long base = ((long long)b * S + s0 + si) * H;
        for (int k = threadIdx.x; k < H; k += blockDim.x) {
            u16 v = f2bf(ysf[base + k] + ysb[base + k]);
            E[base + k] = v;
            tile[si][k] = v;
        }
    }
    __syncthreads();
    for (int idx = threadIdx.x; idx < 32 * H; idx += blockDim.x) {
        int k = idx >> 5, si = idx & 31;
        ET[((long long)b * H + k) * S + s0 + si] = tile[si][k];
    }
}

__global__ void h0_kernel(const float* __restrict__ hf, const float* __restrict__ hb,
                          float* __restrict__ hf32, u16* __restrict__ hnk) {
    int n = blockIdx.x, b = n & 15;
    for (int k = threadIdx.x; k < H; k += blockDim.x) {
        float v = hf[b * H + k] + hb[b * H + k];
        hf32[(long long)n * H + k] = v;
        hnk[(long long)n * H + k] = f2bf(v);
    }
}

// ---------------------------------------------------------------------------
// Fused decoder step: block = batch b (16 blocks, 512 threads, dynamic LDS).
// Writes h_t (bf16) into hall[t] for the batched vocab GEMM; sw/prob per t.
// ---------------------------------------------------------------------------
__global__ __launch_bounds__(512) void fused_step_kernel(
    const float* __restrict__ dgi, const float* __restrict__ dgh,
    float* __restrict__ hf32, u16* __restrict__ hall,
    const u16* __restrict__ decinb,
    const u16* __restrict__ Eb, const u16* __restrict__ ETb,
    const int* __restrict__ lens,
    const float* __restrict__ Wr, const float* __restrict__ br,
    const float* __restrict__ Wg, const float* __restrict__ bg,
    float* __restrict__ probfT, float* __restrict__ swvT,
    float* __restrict__ gout, int t)
{
    extern __shared__ char smem[];
    u16*   hls = (u16*)smem;                                   // [32][HP2]
    float* scs = (float*)(smem + 32 * HP2 * 2);                // [32][SCP]
    u16*   pls = (u16*)(smem + 32 * HP2 * 2 + 32 * SCP * 4);   // [32][PP]
    float* cxs = (float*)(smem + 32 * HP2 * 2 + 32 * SCP * 4 + 32 * PP * 2); // [32][CXP]

    const int b = blockIdx.x;
    const int tid = threadIdx.x, wave = tid >> 6, lane = tid & 63;
    const int fr = lane & 15, kq = lane >> 4;
    const int len = lens[b];

    for (int i = tid; i < 32 * (HP2 - H); i += 512) {
        int r = i / (HP2 - H), c = H + i % (HP2 - H);
        hls[r * HP2 + c] = 0;
    }
    for (int i = tid; i < 2 * HP2; i += 512) hls[30 * HP2 + i] = 0;
    for (int i = tid; i < 2 * PP; i += 512) pls[30 * PP + i] = 0;

    // P0: GRU cell for the 30 slots of this batch
    for (int i = tid; i < 30 * H; i += 512) {
        int slot = i / H, k = i % H;
        int n = slot * 16 + b;
        const float* gi = dgi + ((long long)t * NB + n) * H3;
        const float* gh = dgh + (long long)n * H3;
        float r  = sigm(gi[k] + gh[k]);
        float z  = sigm(gi[H + k] + gh[H + k]);
        float nn = tanhf(gi[2 * H + k] + r * gh[2 * H + k]);
        float h  = hf32[(long long)n * H + k];
        float hn = (1.f - z) * nn + z * h;
        hf32[(long long)n * H + k] = hn;
        u16 hb = f2bf(hn);
        hall[((long long)t * NB + n) * H + k] = hb;
        hls[slot * HP2 + k] = hb;
    }
    __syncthreads();

    // P1: scores[slot][s] = h . E[b][s]   (M=32, N=256, K=400)
    {
        const int nt0 = wave * 2;
        f32x4 acc[2][2];
#pragma unroll
        for (int i = 0; i < 2; ++i)
#pragma unroll
            for (int jj = 0; jj < 2; ++jj) acc[i][jj] = (f32x4){0.f, 0.f, 0.f, 0.f};
        const u16* br0 = Eb + ((long long)b * S + nt0 * 16 + fr) * H + kq * 8;
        const u16* br1 = Eb + ((long long)b * S + (nt0 + 1) * 16 + fr) * H + kq * 8;
        const u16* ar0 = hls + fr * HP2 + kq * 8;
        const u16* ar1 = hls + (16 + fr) * HP2 + kq * 8;
#pragma unroll
        for (int kk = 0; kk < 13; ++kk) {
            bf16x8 av0 = *(const bf16x8*)(ar0 + kk * 32);
            bf16x8 av1 = *(const bf16x8*)(ar1 + kk * 32);
            bf16x8 bv0, bv1;
            if (kk == 12 && kq >= 2) {
                bv0 = (bf16x8){0,0,0,0,0,0,0,0}; bv1 = bv0;
            } else {
                bv0 = *(const bf16x8*)(br0 + kk * 32);
                bv1 = *(const bf16x8*)(br1 + kk * 32);
            }
            acc[0][0] = __builtin_amdgcn_mfma_f32_16x16x32_bf16(av0, bv0, acc[0][0], 0, 0, 0);
            acc[1][0] = __builtin_amdgcn_mfma_f32_16x16x32_bf16(av1, bv0, acc[1][0], 0, 0, 0);
            acc[0][1] = __builtin_amdgcn_mfma_f32_16x16x32_bf16(av0, bv1, acc[0][1], 0, 0, 0);
            acc[1][1] = __builtin_amdgcn_mfma_f32_16x16x32_bf16(av1, bv1, acc[1][1], 0, 0, 0);
        }
#pragma unroll
        for (int i = 0; i < 2; ++i)
#pragma unroll
            for (int jj = 0; jj < 2; ++jj)
#pragma unroll
                for (int r = 0; r < 4; ++r)
                    scs[(i * 16 + kq * 4 + r) * SCP + (nt0 + jj) * 16 + fr] = acc[i][jj][r];
    }
    __syncthreads();

    // P2: softmax rows
    for (int i = 0; i < 4; ++i) {
        int row = wave * 4 + i;
        if (row >= 30) break;
        int n = row * 16 + b;
        float v[4];
        float mx = -3.0e38f;
#pragma unroll
        for (int q = 0; q < 4; ++q) {
            int s = lane + 64 * q;
            float x = (s < len) ? scs[row * SCP + s] : -3.0e38f;
            v[q] = x; mx = fmaxf(mx, x);
        }
        mx = fmaxf(mx, __shfl_xor(mx, 1));  mx = fmaxf(mx, __shfl_xor(mx, 2));
        mx = fmaxf(mx, __shfl_xor(mx, 4));  mx = fmaxf(mx, __shfl_xor(mx, 8));
        mx = fmaxf(mx, __shfl_xor(mx, 16)); mx = fmaxf(mx, __shfl_xor(mx, 32));
        float sum = 0.f;
#pragma unroll
        for (int q = 0; q < 4; ++q) {
            int s = lane + 64 * q;
            float e = (s < len) ? __expf(v[q] - mx) : 0.f;
            v[q] = e; sum += e;
        }
        sum += __shfl_xor(sum, 1);  sum += __shfl_xor(sum, 2);
        sum += __shfl_xor(sum, 4);  sum += __shfl_xor(sum, 8);
        sum += __shfl_xor(sum, 16); sum += __shfl_xor(sum, 32);
        float inv = 1.f / sum;
#pragma unroll
        for (int q = 0; q < 4; ++q) {
            int s = lane + 64 * q;
            float pr = v[q] * inv;
            pls[row * PP + s] = f2bf(pr);
            probfT[((long long)(t * NB + n)) * S + s] = pr;
        }
    }
    __syncthreads();

    // P3: ctx[slot][k] = sum_s prob[slot][s] * ET[b][k][s]
    for (int nt = wave; nt < 25; nt += 8) {
        f32x4 acc0 = (f32x4){0.f,0.f,0.f,0.f}, acc1 = (f32x4){0.f,0.f,0.f,0.f};
        const u16* brow = ETb + ((long long)b * H + nt * 16 + fr) * S + kq * 8;
        const u16* ar0 = pls + fr * PP + kq * 8;
        const u16* ar1 = pls + (16 + fr) * PP + kq * 8;
#pragma unroll
        for (int kk = 0; kk < 8; ++kk) {
            bf16x8 bv  = *(const bf16x8*)(brow + kk * 32);
            bf16x8 av0 = *(const bf16x8*)(ar0 + kk * 32);
            bf16x8 av1 = *(const bf16x8*)(ar1 + kk * 32);
            acc0 = __builtin_amdgcn_mfma_f32_16x16x32_bf16(av0, bv, acc0, 0, 0, 0);
            acc1 = __builtin_amdgcn_mfma_f32_16x16x32_bf16(av1, bv, acc1, 0, 0, 0);
        }
#pragma unroll
        for (int r = 0; r < 4; ++r) {
            cxs[(kq * 4 + r) * CXP + nt * 16 + fr] = acc0[r];
            cxs[(16 + kq * 4 + r) * CXP + nt * 16 + fr] = acc1[r];
        }
    }
    __syncthreads();

    // P4: p_gen switch (+ gate at t==0)
    for (int i = 0; i < 4; ++i) {
        int slot = wave + 8 * i;
        if (slot >= 30) break;
        int n = slot * 16 + b;
        const u16* xrow = decinb + ((long long)t * NB + n) * H;
        float p = 0.f;
        for (int k = lane; k < H; k += 64)
            p += bf2f(hls[slot * HP2 + k]) * Wr[k]
               + cxs[slot * CXP + k] * Wr[H + k]
               + bf2f(xrow[k]) * Wr[2 * H + k];
        p += __shfl_xor(p, 1);  p += __shfl_xor(p, 2);
        p += __shfl_xor(p, 4);  p += __shfl_xor(p, 8);
        p += __shfl_xor(p, 16); p += __shfl_xor(p, 32);
        if (lane == 0) swvT[t * NB + n] = sigm(p + br[0]);
        if (t == 0) {
            for (int g = 0; g < G; ++g) {
                float q = 0.f;
                for (int k = lane; k < H; k += 64)
                    q += cxs[slot * CXP + k] * Wg[g * H + k];
                q += __shfl_xor(q, 1);  q += __shfl_xor(q, 2);
                q += __shfl_xor(q, 4);  q += __shfl_xor(q, 8);
                q += __shfl_xor(q, 16); q += __shfl_xor(q, 32);
                if (lane == 0) gout[(long long)n * G + g] = q + bg[g];
            }
        }
    }
}

// scale all t at once: out[n][t][:] *= sw[t][n] / rowsum[t*NB+n]
__global__ void scale_all_kernel(float* __restrict__ out, const float* __restrict__ swvT,
                                 const float* __restrict__ rowsumT) {
    const int n = blockIdx.x;
    const int col = blockIdx.y * 256 + threadIdx.x;
    if (col >= V) return;
#pragma unroll
    for (int t = 0; t < T; ++t) {
        float f = swvT[t * NB + n] / rowsumT[t * NB + n];
        out[((long long)n * T + t) * V + col] *= f;
    }
}

__global__ void scatter_all_kernel(float* __restrict__ out, const int* __restrict__ story,
                                   const int* __restrict__ lens, const float* __restrict__ swvT,
                                   const float* __restrict__ probfT) {
    const int n = blockIdx.x, t = blockIdx.y, b = n & 15, s = threadIdx.x;
    if (s < lens[b]) {
        int tok = story[b * S + s];
        atomicAdd(out + ((long long)n * T + t) * V + tok,
                  (1.f - swvT[t * NB + n]) * probfT[((long long)(t * NB + n)) * S + s]);
    }
}

// ---------------------------------------------------------------------------
extern "C" void kernel_launch(void* const* d_in, const int* in_sizes, int n_in,
                              void* d_out, int out_size, void* d_ws, size_t ws_size,
                              hipStream_t stream) {
    const int*   story = (const int*)d_in[0];
    const int*   lens  = (const int*)d_in[1];
    const int*   tgt   = (const int*)d_in[2];
    const int*   dom   = (const int*)d_in[3];
    const int*   sidx  = (const int*)d_in[4];
    const float* emb   = (const float*)d_in[5];
    const float* wihf  = (const float*)d_in[6];
    const float* whhf  = (const float*)d_in[7];
    const float* bihf  = (const float*)d_in[8];
    const float* bhhf  = (const float*)d_in[9];
    const float* wihb  = (const float*)d_in[10];
    const float* whhb  = (const float*)d_in[11];
    const float* bihb  = (const float*)d_in[12];
    const float* bhhb  = (const float*)d_in[13];
    const float* dwih  = (const float*)d_in[14];
    const float* dwhh  = (const float*)d_in[15];
    const float* dbih  = (const float*)d_in[16];
    const float* dbhh  = (const float*)d_in[17];
    const float* Wr    = (const float*)d_in[18];
    const float* br    = (const float*)d_in[19];
    const float* Wg    = (const float*)d_in[20];
    const float* bg    = (const float*)d_in[21];
    const float* slt   = (const float*)d_in[22];
    float* out = (float*)d_out;

    char* wsb = (char*)d_ws;
    size_t off = 0;
    auto alloc = [&](size_t bytes) -> char* {
        char* p = wsb + off;
        off += (bytes + 255) & ~(size_t)255;
        return p;
    };
    u16*   embb   = (u16*)alloc((size_t)V * H * 2);
    u16*   wihfb  = (u16*)alloc((size_t)H3 * H * 2);
    u16*   wihbb  = (u16*)alloc((size_t)H3 * H * 2);
    u16*   dwihb  = (u16*)alloc((size_t)H3 * H * 2);
    u16*   dwhhb  = (u16*)alloc((size_t)H3 * H * 2);
    u16*   wencp  = (u16*)alloc((size_t)2 * ENBLK * EROWS * EKP * 2);
    unsigned* hbuf = (unsigned*)alloc((size_t)2 * 2 * B * EKP * 4);
    int*   flags  = (int*)alloc((size_t)2 * ENBLK * 4);
    u16*   xb     = (u16*)alloc((size_t)S * B * H * 2);
    u16*   decinb = (u16*)alloc((size_t)T * NB * H * 2);
    float* gif    = (float*)alloc((size_t)S * B * H3 * 4);
    float* gib    = (float*)alloc((size_t)S * B * H3 * 4);
    float* dgi    = (float*)alloc((size_t)T * NB * H3 * 4);
    float* ysf    = (float*)alloc((size_t)B * S * H * 4);
    float* ysb    = (float*)alloc((size_t)B * S * H * 4);
    float* hfv    = (float*)alloc((size_t)B * H * 4);
    float* hbv    = (float*)alloc((size_t)B * H * 4);
    u16*   Eb     = (u16*)alloc((size_t)B * S * H * 2);
    u16*   ETb    = (u16*)alloc((size_t)B * H * S * 2);
    float* hf32   = (float*)alloc((size_t)NB * H * 4);
    u16*   hnk    = (u16*)alloc((size_t)NB * H * 2);
    u16*   hall   = (u16*)alloc((size_t)T * NB * H * 2);
    float* dgh    = (float*)alloc((size_t)NB * H3 * 4);
    float* probfT = (float*)alloc((size_t)T * NB * S * 4);
    float* swvT   = (float*)alloc((size_t)T * NB * 4);
    float* rowsumT = (float*)alloc((size_t)T * NB * 4);
    (void)ws_size; (void)in_sizes; (void)n_in; (void)out_size;

    auto launch_gemm = [&](const u16* A, const u16* Bt, const float* bias, float* C,
                           int M, int N, int K, int lda, int ldb, long long ldc,
                           long long sA, long long sB, long long sC, int nb,
                           int mode, float* rs) {
        dim3 g((M + 63) / 64, (N + 63) / 64, nb);
        gemm_bt<<<g, 256, 0, stream>>>(A, Bt, bias, C, M, N, K, lda, ldb, ldc,
                                       sA, sB, sC, mode, rs);
    };

    hipFuncSetAttribute((const void*)fused_step_kernel,
                        hipFuncAttributeMaxDynamicSharedMemorySize, FUSED_LDS);

    // ---- setup: casts, embeddings, input-side GEMMs -----------------------
    cvt_bf16_kernel<<<2048, 256, 0, stream>>>(emb, embb, V * H);
    cvt4_kernel<<<1024, 256, 0, stream>>>(wihf, wihb, dwih, dwhh,
                                          wihfb, wihbb, dwihb, dwhhb, H3 * H);
    {
        const int total = 2 * ENBLK * EROWS * EKP;
        prep_wenc_kernel<<<(total + 255) / 256, 256, 0, stream>>>(whhf, whhb, wencp);
    }
    embed_story_kernel<<<S * B, 256, 0, stream>>>(story, embb, xb);
    { dim3 g(NB, T); build_decin_kernel<<<g, 256, 0, stream>>>(tgt, dom, sidx, slt, embb, decinb); }

    launch_gemm(xb, wihfb, bihf, gif, S * B, H3, H, H, H, H3, 0, 0, 0, 1, 0, nullptr);
    launch_gemm(xb, wihbb, bihb, gib, S * B, H3, H, H, H, H3, 0, 0, 0, 1, 0, nullptr);
    launch_gemm(decinb, dwihb, dbih, dgi, T * NB, H3, H, H, H, H3, 0, 0, 0, 1, 0, nullptr);

    // ---- encoder recurrence (protocol v5: relaxed flag) -------------------
    hipMemsetAsync(flags, 0, (size_t)2 * ENBLK * 4, stream);
    hipMemsetAsync(hbuf, 0, (size_t)2 * 2 * B * EKP * 4, stream);
    hipMemsetAsync(rowsumT, 0, (size_t)T * NB * 4, stream);
    enc_rnn2_kernel<<<2 * ENBLK, 256, 0, stream>>>(wencp, bhhf, bhhb, gif, gib, lens,
                                                   hbuf, flags, ysf, ysb, hfv, hbv);
    { dim3 g(B, S / 32); packE_kernel<<<g, 256, 0, stream>>>(ysf, ysb, Eb, ETb); }
    h0_kernel<<<NB, 256, 0, stream>>>(hfv, hbv, hf32, hnk);

    // ---- decoder: sequential chain (2 launches/step) ----------------------
    for (int t = 0; t < T; ++t) {
        const u16* hprev = (t == 0) ? hnk : hall + (size_t)(t - 1) * NB * H;
        launch_gemm(hprev, dwhhb, dbhh, dgh, NB, H3, H, H, H, H3, 0, 0, 0, 1, 0, nullptr);
        fused_step_kernel<<<16, 512, FUSED_LDS, stream>>>(
            dgi, dgh, hf32, hall, decinb, Eb, ETb, lens, Wr, br, Wg, bg,
            probfT, swvT, out + (size_t)NB * T * V, t);
    }

    // ---- batched vocab projection: one GEMM over all (t, n) rows ----------
    launch_gemm(hall, embb, nullptr, out, T * NB, V, H, H, H, V,
                0, 0, 0, 1, 2, rowsumT);
    { dim3 g(NB, (V + 255) / 256); scale_all_kernel<<<g, 256, 0, stream>>>(out, swvT, rowsumT); }
    { dim3 g(NB, T); scatter_all_kernel<<<g, 256, 0, stream>>>(out, story, lens, swvT, probfT); }
}

// Round 8
// 2472.747 us; speedup vs baseline: 2.1527x; 1.0570x over previous
//
#include <hip/hip_runtime.h>
#include <hip/hip_bf16.h>

typedef unsigned short u16;
typedef __attribute__((ext_vector_type(8))) short bf16x8;
typedef __attribute__((ext_vector_type(4))) float f32x4;
typedef __attribute__((ext_vector_type(4))) unsigned u32x4;

static constexpr int V = 20000, H = 400, B = 16, S = 256, NSLOT = 30, T = 10, G = 3;
static constexpr int H3 = 3 * H;           // 1200
static constexpr int NB = NSLOT * B;       // 480
// encoder partition
static constexpr int ENBLK = 20;           // blocks per direction
static constexpr int ESL   = 20;           // h components per block (400/20)
static constexpr int EROWS = 64;           // padded weight rows per block
static constexpr int EKP   = 416;          // padded K
// fused decoder LDS strides
static constexpr int HP2 = 424;            // h_lds row stride (u16)
static constexpr int SCP = 260;            // scores row stride (f32)
static constexpr int PP  = 264;            // prob row stride (u16)
static constexpr int CXP = 404;            // ctx row stride (f32)
static constexpr int FUSED_LDS = 32*HP2*2 + 32*SCP*4 + 32*PP*2 + 32*CXP*4; // 129024

__device__ __forceinline__ float bf2f(u16 v) {
    union { unsigned u; float f; } x; x.u = ((unsigned)v) << 16; return x.f;
}
__device__ __forceinline__ u16 f2bf(float f) {
    union { float f; unsigned u; } x; x.f = f;
    unsigned r = x.u + 0x7fffu + ((x.u >> 16) & 1u);   // round-to-nearest-even
    return (u16)(r >> 16);
}
__device__ __forceinline__ float sigm(float v) { return 1.f / (1.f + __expf(-v)); }

// ---------------------------------------------------------------------------
// Generic batched GEMM: C[m][n] = sum_k A[m][k] * Bt[n][k]  (+bias[n])
// mode 0: plain (+bias). mode 1: C=exp(acc)+rowsum, ldc layout.
// mode 2: C=exp(acc)+rowsum, vocab layout: row=t*NB+n -> C[((n*T)+t)*V + col].
// ---------------------------------------------------------------------------
__global__ __launch_bounds__(256) void gemm_bt(
    const u16* __restrict__ A, const u16* __restrict__ Bt,
    const float* __restrict__ bias, float* __restrict__ C,
    int M, int N, int K, int lda, int ldb, long long ldc,
    long long sA, long long sB, long long sC,
    int mode, float* __restrict__ rowsum)
{
    __shared__ u16 As[64][40];
    __shared__ u16 Bs[64][40];
    const int bz = blockIdx.z;
    A  += (long long)bz * sA;
    Bt += (long long)bz * sB;
    C  += (long long)bz * sC;
    const int m0 = blockIdx.x * 64, n0 = blockIdx.y * 64;
    const int tid = threadIdx.x, wave = tid >> 6, lane = tid & 63;
    const int wm = (wave >> 1) * 32, wn = (wave & 1) * 32;
    const int srow = tid >> 2, scol = (tid & 3) * 8;
    const int fr = lane & 15, kq = lane >> 4;
    f32x4 acc[2][2];
#pragma unroll
    for (int i = 0; i < 2; ++i)
#pragma unroll
        for (int j = 0; j < 2; ++j) acc[i][j] = (f32x4){0.f, 0.f, 0.f, 0.f};

    for (int k0 = 0; k0 < K; k0 += 32) {
        {
            int gr = m0 + srow, gc = k0 + scol;
            bf16x8 v;
            if (gr < M && gc + 8 <= K) {
                v = *(const bf16x8*)(A + (long long)gr * lda + gc);
            } else {
                short tmp[8];
#pragma unroll
                for (int j = 0; j < 8; ++j)
                    tmp[j] = (gr < M && gc + j < K) ? (short)A[(long long)gr * lda + gc + j] : (short)0;
                v = *(bf16x8*)tmp;
            }
            *(bf16x8*)&As[srow][scol] = v;
        }
        {
            int gr = n0 + srow, gc = k0 + scol;
            bf16x8 v;
            if (gr < N && gc + 8 <= K) {
                v = *(const bf16x8*)(Bt + (long long)gr * ldb + gc);
            } else {
                short tmp[8];
#pragma unroll
                for (int j = 0; j < 8; ++j)
                    tmp[j] = (gr < N && gc + j < K) ? (short)Bt[(long long)gr * ldb + gc + j] : (short)0;
                v = *(bf16x8*)tmp;
            }
            *(bf16x8*)&Bs[srow][scol] = v;
        }
        __syncthreads();
        bf16x8 af[2], bfr[2];
#pragma unroll
        for (int i = 0; i < 2; ++i) af[i]  = *(const bf16x8*)&As[wm + i * 16 + fr][kq * 8];
#pragma unroll
        for (int j = 0; j < 2; ++j) bfr[j] = *(const bf16x8*)&Bs[wn + j * 16 + fr][kq * 8];
#pragma unroll
        for (int i = 0; i < 2; ++i)
#pragma unroll
            for (int j = 0; j < 2; ++j)
                acc[i][j] = __builtin_amdgcn_mfma_f32_16x16x32_bf16(af[i], bfr[j], acc[i][j], 0, 0, 0);
        __syncthreads();
    }

#pragma unroll
    for (int i = 0; i < 2; ++i)
#pragma unroll
        for (int j = 0; j < 2; ++j) {
            int col = n0 + wn + j * 16 + fr;
            float bv = (bias != nullptr && col < N) ? bias[col] : 0.f;
#pragma unroll
            for (int r = 0; r < 4; ++r) {
                int row = m0 + wm + i * 16 + kq * 4 + r;
                bool ok = (row < M) && (col < N);
                float v = acc[i][j][r] + bv;
                if (mode >= 1) { v = ok ? __expf(v) : 0.f; acc[i][j][r] = v; }
                if (ok) {
                    long long coff;
                    if (mode == 2)
                        coff = ((long long)(row % NB) * T + (row / NB)) * (long long)V + col;
                    else
                        coff = (long long)row * ldc + col;
                    C[coff] = v;
                }
            }
        }
    if (mode >= 1) {
#pragma unroll
        for (int i = 0; i < 2; ++i)
#pragma unroll
            for (int r = 0; r < 4; ++r) {
                float s = acc[i][0][r] + acc[i][1][r];
                s += __shfl_xor(s, 1); s += __shfl_xor(s, 2);
                s += __shfl_xor(s, 4); s += __shfl_xor(s, 8);
                if (fr == 0) {
                    int row = m0 + wm + i * 16 + kq * 4 + r;
                    if (row < M) atomicAdd(&rowsum[row], s);
                }
            }
    }
}

// ---------------------------------------------------------------------------
// small utility kernels
// ---------------------------------------------------------------------------
__global__ void cvt_bf16_kernel(const float* __restrict__ src, u16* __restrict__ dst, int n) {
    for (int i = blockIdx.x * blockDim.x + threadIdx.x; i < n; i += gridDim.x * blockDim.x)
        dst[i] = f2bf(src[i]);
}

__global__ void cvt4_kernel(const float* __restrict__ a, const float* __restrict__ b,
                            const float* __restrict__ c, const float* __restrict__ d,
                            u16* __restrict__ da, u16* __restrict__ db,
                            u16* __restrict__ dc, u16* __restrict__ dd, int n) {
    for (int i = blockIdx.x * blockDim.x + threadIdx.x; i < n; i += gridDim.x * blockDim.x) {
        da[i] = f2bf(a[i]); db[i] = f2bf(b[i]); dc[i] = f2bf(c[i]); dd[i] = f2bf(d[i]);
    }
}

// weight prep for the distributed encoder: dst[dir][j][rloc][k], rloc = g*20+c
__global__ void prep_wenc_kernel(const float* __restrict__ whhf, const float* __restrict__ whhb,
                                 u16* __restrict__ dst) {
    int idx = blockIdx.x * 256 + threadIdx.x;
    const int total = 2 * ENBLK * EROWS * EKP;
    if (idx >= total) return;
    int k = idx % EKP; int r = idx / EKP;
    int rloc = r % EROWS; r /= EROWS;
    int j = r % ENBLK; int dir = r / ENBLK;
    u16 v = 0;
    if (k < H && rloc < 3 * ESL) {
        int g = rloc / ESL, c = rloc % ESL;
        const float* W = dir ? whhb : whhf;
        v = f2bf(W[(long long)(g * H + j * ESL + c) * H + k]);
    }
    dst[idx] = v;
}

__global__ void embed_story_kernel(const int* __restrict__ story, const u16* __restrict__ embb,
                                   u16* __restrict__ xb) {
    int row = blockIdx.x;                 // row = s*16 + b
    int s = row >> 4, b = row & 15;
    int tok = story[b * S + s];
    const u16* e = embb + (long long)tok * H;
    u16* d = xb + (long long)row * H;
    for (int k = threadIdx.x; k < H; k += blockDim.x) d[k] = e[k];
}

__global__ void build_decin_kernel(const int* __restrict__ tgt, const int* __restrict__ dom,
                                   const int* __restrict__ sidx, const float* __restrict__ slt,
                                   const u16* __restrict__ embb, u16* __restrict__ decin) {
    int n = blockIdx.x, t = blockIdx.y;
    int b = n & 15, slot = n >> 4;
    u16* d = decin + ((long long)t * NB + n) * H;
    if (t == 0) {
        const float* s1 = slt + (long long)dom[slot] * H;
        const float* s2 = slt + (long long)sidx[slot] * H;
        for (int k = threadIdx.x; k < H; k += blockDim.x) d[k] = f2bf(s1[k] + s2[k]);
    } else {
        int tok = tgt[(b * NSLOT + slot) * T + (t - 1)];
        const u16* e = embb + (long long)tok * H;
        for (int k = threadIdx.x; k < H; k += blockDim.x) d[k] = e[k];
    }
}

// ---------------------------------------------------------------------------
// Distributed encoder recurrence — protocol v6 (rotating buffers, NO fences):
//  - hbuf[dir][t][b][EKP] : step t's h is published to a FRESH region via
//    relaxed agent (sc1 write-through) stores -> lands at L3. Readers use
//    plain dwordx4 loads at never-before-read addresses -> guaranteed L2
//    cold miss -> serviced from L3 -> fresh. No acquire buffer_inv needed.
//  - flags[dir][t][j] : store-only (set to 1) after __syncthreads (vmcnt0
//    drain). Pollers use relaxed sc1 loads (always serviced at L3).
//  - rotation also removes the ping-pong 2-step skew hazard entirely.
// ---------------------------------------------------------------------------
__global__ __launch_bounds__(256) void enc_rnn2_kernel(
    const u16* __restrict__ wencp,
    const float* __restrict__ bhhf, const float* __restrict__ bhhb,
    const float* __restrict__ gif, const float* __restrict__ gib,
    const int* __restrict__ lens,
    unsigned* __restrict__ hbuf, int* __restrict__ flags,
    float* __restrict__ ysf, float* __restrict__ ysb,
    float* __restrict__ hfo, float* __restrict__ hbo)
{
    const int bid = blockIdx.x;
    const int dir = bid / ENBLK, j = bid % ENBLK;
    const float* bhh = dir ? bhhb : bhhf;
    const float* gi  = dir ? gib  : gif;
    float* ys = dir ? ysb : ysf;
    float* ho = dir ? hbo : hfo;

    __shared__ u16 wlds[EROWS * EKP];      // 53248 B
    __shared__ float ghs[EROWS * 17];      // 4352 B

    const int tid = threadIdx.x, wave = tid >> 6, lane = tid & 63;
    const int fr = lane & 15, kq = lane >> 4;

    const u16* wsrc = wencp + (long long)(dir * ENBLK + j) * EROWS * EKP;
    for (int i = tid * 8; i < EROWS * EKP; i += 256 * 8)
        *(bf16x8*)&wlds[i] = *(const bf16x8*)&wsrc[i];
    for (int i = tid; i < EROWS * 17; i += 256) ghs[i] = 0.f;

    const int p0 = tid, p1 = 256 + tid;
    const bool has1 = (tid < 64);
    const int b0 = p0 / ESL, kl0 = p0 % ESL;
    const int b1 = has1 ? p1 / ESL : 0, kl1 = has1 ? p1 % ESL : 0;
    const int k0 = j * ESL;
    const int len0 = lens[b0];
    const int len1 = has1 ? lens[b1] : 0;
    const float bhr0 = bhh[k0 + kl0], bhz0 = bhh[H + k0 + kl0], bhn0 = bhh[2 * H + k0 + kl0];
    const float bhr1 = has1 ? bhh[k0 + kl1] : 0.f;
    const float bhz1 = has1 ? bhh[H + k0 + kl1] : 0.f;
    const float bhn1 = has1 ? bhh[2 * H + k0 + kl1] : 0.f;
    float h0r = 0.f, h1r = 0.f;

    unsigned* hb_d = hbuf + (long long)dir * S * B * EKP;
    int* flg_d = flags + dir * S * ENBLK;
    const u16* arow = &wlds[(wave * 16 + fr) * EKP + kq * 8];
    __syncthreads();

    for (int t = 0; t < S; ++t) {
        const int s = dir ? (S - 1 - t) : t;
        const float* gbase = gi + (long long)s * B * H3;
        float gr0 = gbase[b0 * H3 + k0 + kl0];
        float gz0 = gbase[b0 * H3 + H + k0 + kl0];
        float gn0 = gbase[b0 * H3 + 2 * H + k0 + kl0];
        float gr1 = 0.f, gz1 = 0.f, gn1 = 0.f;
        if (has1) {
            gr1 = gbase[b1 * H3 + k0 + kl1];
            gz1 = gbase[b1 * H3 + H + k0 + kl1];
            gn1 = gbase[b1 * H3 + 2 * H + k0 + kl1];
        }

        f32x4 acc = (f32x4){0.f, 0.f, 0.f, 0.f};
        if (t > 0) {
            // relaxed sc1 spin on step-(t-1) flags (no cache maintenance)
            const int* fl = flg_d + (t - 1) * ENBLK;
            for (;;) {
                int v = 1;
                if (lane < ENBLK)
                    v = __hip_atomic_load(&fl[lane], __ATOMIC_RELAXED,
                                          __HIP_MEMORY_SCOPE_AGENT);
                if (__all(v != 0)) break;
                __builtin_amdgcn_s_sleep(2);
            }
            asm volatile("" ::: "memory");   // keep hbuf reads after the poll
            // plain loads at never-before-read addresses: L2 cold miss -> L3
            const unsigned* hrow = hb_d + ((long long)(t - 1) * B + fr) * EKP + kq * 8;
            f32x4 acch = (f32x4){0.f, 0.f, 0.f, 0.f};
            f32x4 accl = (f32x4){0.f, 0.f, 0.f, 0.f};
#pragma unroll
            for (int kk = 0; kk < 13; ++kk) {
                u32x4 a = *(const u32x4*)(hrow + kk * 32);
                u32x4 b = *(const u32x4*)(hrow + kk * 32 + 4);
                union { unsigned u[4]; bf16x8 v; } hi, lo;
                hi.u[0] = __builtin_amdgcn_perm(a[1], a[0], 0x05040100u);
                hi.u[1] = __builtin_amdgcn_perm(a[3], a[2], 0x05040100u);
                hi.u[2] = __builtin_amdgcn_perm(b[1], b[0], 0x05040100u);
                hi.u[3] = __builtin_amdgcn_perm(b[3], b[2], 0x05040100u);
                lo.u[0] = __builtin_amdgcn_perm(a[1], a[0], 0x07060302u);
                lo.u[1] = __builtin_amdgcn_perm(a[3], a[2], 0x07060302u);
                lo.u[2] = __builtin_amdgcn_perm(b[1], b[0], 0x07060302u);
                lo.u[3] = __builtin_amdgcn_perm(b[3], b[2], 0x07060302u);
                bf16x8 av = *(const bf16x8*)(arow + kk * 32);
                acch = __builtin_amdgcn_mfma_f32_16x16x32_bf16(av, hi.v, acch, 0, 0, 0);
                accl = __builtin_amdgcn_mfma_f32_16x16x32_bf16(av, lo.v, accl, 0, 0, 0);
            }
            acc = acch + accl;
        }
#pragma unroll
        for (int r = 0; r < 4; ++r) ghs[(wave * 16 + kq * 4 + r) * 17 + fr] = acc[r];
        __syncthreads();

        unsigned* hpub = hb_d + (long long)t * B * EKP;
        {
            float ghr = ghs[kl0 * 17 + b0];
            float ghz = ghs[(ESL + kl0) * 17 + b0];
            float ghn = ghs[(2 * ESL + kl0) * 17 + b0];
            float rg = sigm(gr0 + ghr + bhr0);
            float zg = sigm(gz0 + ghz + bhz0);
            float ng = tanhf(gn0 + rg * (ghn + bhn0));
            float hn = (1.f - zg) * ng + zg * h0r;
            bool msk = s < len0;
            float y = msk ? hn : 0.f;
            if (msk) h0r = hn;
            ys[((long long)(b0 * S + s)) * H + k0 + kl0] = y;
            u16 hi = f2bf(h0r);
            unsigned packed = (unsigned)hi | ((unsigned)f2bf(h0r - bf2f(hi)) << 16);
            __hip_atomic_store(&hpub[b0 * EKP + k0 + kl0], packed, __ATOMIC_RELAXED,
                               __HIP_MEMORY_SCOPE_AGENT);
        }
        if (has1) {
            float ghr = ghs[kl1 * 17 + b1];
            float ghz = ghs[(ESL + kl1) * 17 + b1];
            float ghn = ghs[(2 * ESL + kl1) * 17 + b1];
            float rg = sigm(gr1 + ghr + bhr1);
            float zg = sigm(gz1 + ghz + bhz1);
            float ng = tanhf(gn1 + rg * (ghn + bhn1));
            float hn = (1.f - zg) * ng + zg * h1r;
            bool msk = s < len1;
            float y = msk ? hn : 0.f;
            if (msk) h1r = hn;
            ys[((long long)(b1 * S + s)) * H + k0 + kl1] = y;
            u16 hi = f2bf(h1r);
            unsigned packed = (unsigned)hi | ((unsigned)f2bf(h1r - bf2f(hi)) << 16);
            __hip_atomic_store(&hpub[b1 * EKP + k0 + kl1], packed, __ATOMIC_RELAXED,
                               __HIP_MEMORY_SCOPE_AGENT);
        }
        // barrier drains every wave's write-through publishes (vmcnt0 -> L3)
        __syncthreads();
        if (tid == 0)
            __hip_atomic_store(&flg_d[t * ENBLK + j], 1, __ATOMIC_RELAXED,
                               __HIP_MEMORY_SCOPE_AGENT);
    }
    ho[b0 * H + k0 + kl0] = h0r;
    if (has1) ho[b1 * H + k0 + kl1] = h1r;
}

// E = ys_f + ys_b (bf16, [b][s][k]) and ET (bf16, [b][k][s])
__global__ void packE_kernel(const float* __restrict__ ysf, const float* __restrict__ ysb,
                             u16* __restrict__ E, u16* __restrict__ ET) {
    __shared__ u16 tile[32][400];
    const int b = blockIdx.x, s0 = blockIdx.y * 32;
    for (int si = 0; si < 32; ++si) {
        const long long base = ((long long)b * S + s0 + si) * H;
        for (int k = threadIdx.x; k < H; k += blockDim.x) {
            u16 v = f2bf(ysf[base + k] + ysb[base + k]);
            E[base + k] = v;
            tile[si][k] = v;
        }
    }
    __syncthreads();
    for (int idx = threadIdx.x; idx < 32 * H; idx += blockDim.x) {
        int k = idx >> 5, si = idx & 31;
        ET[((long long)b * H + k) * S + s0 + si] = tile[si][k];
    }
}

__global__ void h0_kernel(const float* __restrict__ hf, const float* __restrict__ hb,
                          float* __restrict__ hf32, u16* __restrict__ hnk) {
    int n = blockIdx.x, b = n & 15;
    for (int k = threadIdx.x; k < H; k += blockDim.x) {
        float v = hf[b * H + k] + hb[b * H + k];
        hf32[(long long)n * H + k] = v;
        hnk[(long long)n * H + k] = f2bf(v);
    }
}

// ---------------------------------------------------------------------------
// Fused decoder step: block = batch b (16 blocks, 512 threads, dynamic LDS).
// Writes h_t (bf16) into hall[t] for the batched vocab GEMM; sw/prob per t.
// ---------------------------------------------------------------------------
__global__ __launch_bounds__(512) void fused_step_kernel(
    const float* __restrict__ dgi, const float* __restrict__ dgh,
    float* __restrict__ hf32, u16* __restrict__ hall,
    const u16* __restrict__ decinb,
    const u16* __restrict__ Eb, const u16* __restrict__ ETb,
    const int* __restrict__ lens,
    const float* __restrict__ Wr, const float* __restrict__ br,
    const float* __restrict__ Wg, const float* __restrict__ bg,
    float* __restrict__ probfT, float* __restrict__ swvT,
    float* __restrict__ gout, int t)
{
    extern __shared__ char smem[];
    u16*   hls = (u16*)smem;                                   // [32][HP2]
    float* scs = (float*)(smem + 32 * HP2 * 2);                // [32][SCP]
    u16*   pls = (u16*)(smem + 32 * HP2 * 2 + 32 * SCP * 4);   // [32][PP]
    float* cxs = (float*)(smem + 32 * HP2 * 2 + 32 * SCP * 4 + 32 * PP * 2); // [32][CXP]

    const int b = blockIdx.x;
    const int tid = threadIdx.x, wave = tid >> 6, lane = tid & 63;
    const int fr = lane & 15, kq = lane >> 4;
    const int len = lens[b];

    for (int i = tid; i < 32 * (HP2 - H); i += 512) {
        int r = i / (HP2 - H), c = H + i % (HP2 - H);
        hls[r * HP2 + c] = 0;
    }
    for (int i = tid; i < 2 * HP2; i += 512) hls[30 * HP2 + i] = 0;
    for (int i = tid; i < 2 * PP; i += 512) pls[30 * PP + i] = 0;

    // P0: GRU cell for the 30 slots of this batch
    for (int i = tid; i < 30 * H; i += 512) {
        int slot = i / H, k = i % H;
        int n = slot * 16 + b;
        const float* gi = dgi + ((long long)t * NB + n) * H3;
        const float* gh = dgh + (long long)n * H3;
        float r  = sigm(gi[k] + gh[k]);
        float z  = sigm(gi[H + k] + gh[H + k]);
        float nn = tanhf(gi[2 * H + k] + r * gh[2 * H + k]);
        float h  = hf32[(long long)n * H + k];
        float hn = (1.f - z) * nn + z * h;
        hf32[(long long)n * H + k] = hn;
        u16 hb = f2bf(hn);
        hall[((long long)t * NB + n) * H + k] = hb;
        hls[slot * HP2 + k] = hb;
    }
    __syncthreads();

    // P1: scores[slot][s] = h . E[b][s]   (M=32, N=256, K=400)
    {
        const int nt0 = wave * 2;
        f32x4 acc[2][2];
#pragma unroll
        for (int i = 0; i < 2; ++i)
#pragma unroll
            for (int jj = 0; jj < 2; ++jj) acc[i][jj] = (f32x4){0.f, 0.f, 0.f, 0.f};
        const u16* br0 = Eb + ((long long)b * S + nt0 * 16 + fr) * H + kq * 8;
        const u16* br1 = Eb + ((long long)b * S + (nt0 + 1) * 16 + fr) * H + kq * 8;
        const u16* ar0 = hls + fr * HP2 + kq * 8;
        const u16* ar1 = hls + (16 + fr) * HP2 + kq * 8;
#pragma unroll
        for (int kk = 0; kk < 13; ++kk) {
            bf16x8 av0 = *(const bf16x8*)(ar0 + kk * 32);
            bf16x8 av1 = *(const bf16x8*)(ar1 + kk * 32);
            bf16x8 bv0, bv1;
            if (kk == 12 && kq >= 2) {
                bv0 = (bf16x8){0,0,0,0,0,0,0,0}; bv1 = bv0;
            } else {
                bv0 = *(const bf16x8*)(br0 + kk * 32);
                bv1 = *(const bf16x8*)(br1 + kk * 32);
            }
            acc[0][0] = __builtin_amdgcn_mfma_f32_16x16x32_bf16(av0, bv0, acc[0][0], 0, 0, 0);
            acc[1][0] = __builtin_amdgcn_mfma_f32_16x16x32_bf16(av1, bv0, acc[1][0], 0, 0, 0);
            acc[0][1] = __builtin_amdgcn_mfma_f32_16x16x32_bf16(av0, bv1, acc[0][1], 0, 0, 0);
            acc[1][1] = __builtin_amdgcn_mfma_f32_16x16x32_bf16(av1, bv1, acc[1][1], 0, 0, 0);
        }
#pragma unroll
        for (int i = 0; i < 2; ++i)
#pragma unroll
            for (int jj = 0; jj < 2; ++jj)
#pragma unroll
                for (int r = 0; r < 4; ++r)
                    scs[(i * 16 + kq * 4 + r) * SCP + (nt0 + jj) * 16 + fr] = acc[i][jj][r];
    }
    __syncthreads();

    // P2: softmax rows
    for (int i = 0; i < 4; ++i) {
        int row = wave * 4 + i;
        if (row >= 30) break;
        int n = row * 16 + b;
        float v[4];
        float mx = -3.0e38f;
#pragma unroll
        for (int q = 0; q < 4; ++q) {
            int s = lane + 64 * q;
            float x = (s < len) ? scs[row * SCP + s] : -3.0e38f;
            v[q] = x; mx = fmaxf(mx, x);
        }
        mx = fmaxf(mx, __shfl_xor(mx, 1));  mx = fmaxf(mx, __shfl_xor(mx, 2));
        mx = fmaxf(mx, __shfl_xor(mx, 4));  mx = fmaxf(mx, __shfl_xor(mx, 8));
        mx = fmaxf(mx, __shfl_xor(mx, 16)); mx = fmaxf(mx, __shfl_xor(mx, 32));
        float sum = 0.f;
#pragma unroll
        for (int q = 0; q < 4; ++q) {
            int s = lane + 64 * q;
            float e = (s < len) ? __expf(v[q] - mx) : 0.f;
            v[q] = e; sum += e;
        }
        sum += __shfl_xor(sum, 1);  sum += __shfl_xor(sum, 2);
        sum += __shfl_xor(sum, 4);  sum += __shfl_xor(sum, 8);
        sum += __shfl_xor(sum, 16); sum += __shfl_xor(sum, 32);
        float inv = 1.f / sum;
#pragma unroll
        for (int q = 0; q < 4; ++q) {
            int s = lane + 64 * q;
            float pr = v[q] * inv;
            pls[row * PP + s] = f2bf(pr);
            probfT[((long long)(t * NB + n)) * S + s] = pr;
        }
    }
    __syncthreads();

    // P3: ctx[slot][k] = sum_s prob[slot][s] * ET[b][k][s]
    for (int nt = wave; nt < 25; nt += 8) {
        f32x4 acc0 = (f32x4){0.f,0.f,0.f,0.f}, acc1 = (f32x4){0.f,0.f,0.f,0.f};
        const u16* brow = ETb + ((long long)b * H + nt * 16 + fr) * S + kq * 8;
        const u16* ar0 = pls + fr * PP + kq * 8;
        const u16* ar1 = pls + (16 + fr) * PP + kq * 8;
#pragma unroll
        for (int kk = 0; kk < 8; ++kk) {
            bf16x8 bv  = *(const bf16x8*)(brow + kk * 32);
            bf16x8 av0 = *(const bf16x8*)(ar0 + kk * 32);
            bf16x8 av1 = *(const bf16x8*)(ar1 + kk * 32);
            acc0 = __builtin_amdgcn_mfma_f32_16x16x32_bf16(av0, bv, acc0, 0, 0, 0);
            acc1 = __builtin_amdgcn_mfma_f32_16x16x32_bf16(av1, bv, acc1, 0, 0, 0);
        }
#pragma unroll
        for (int r = 0; r < 4; ++r) {
            cxs[(kq * 4 + r) * CXP + nt * 16 + fr] = acc0[r];
            cxs[(16 + kq * 4 + r) * CXP + nt * 16 + fr] = acc1[r];
        }
    }
    __syncthreads();

    // P4: p_gen switch (+ gate at t==0)
    for (int i = 0; i < 4; ++i) {
        int slot = wave + 8 * i;
        if (slot >= 30) break;
        int n = slot * 16 + b;
        const u16* xrow = decinb + ((long long)t * NB + n) * H;
        float p = 0.f;
        for (int k = lane; k < H; k += 64)
            p += bf2f(hls[slot * HP2 + k]) * Wr[k]
               + cxs[slot * CXP + k] * Wr[H + k]
               + bf2f(xrow[k]) * Wr[2 * H + k];
        p += __shfl_xor(p, 1);  p += __shfl_xor(p, 2);
        p += __shfl_xor(p, 4);  p += __shfl_xor(p, 8);
        p += __shfl_xor(p, 16); p += __shfl_xor(p, 32);
        if (lane == 0) swvT[t * NB + n] = sigm(p + br[0]);
        if (t == 0) {
            for (int g = 0; g < G; ++g) {
                float q = 0.f;
                for (int k = lane; k < H; k += 64)
                    q += cxs[slot * CXP + k] * Wg[g * H + k];
                q += __shfl_xor(q, 1);  q += __shfl_xor(q, 2);
                q += __shfl_xor(q, 4);  q += __shfl_xor(q, 8);
                q += __shfl_xor(q, 16); q += __shfl_xor(q, 32);
                if (lane == 0) gout[(long long)n * G + g] = q + bg[g];
            }
        }
    }
}

// scale all t at once: out[n][t][:] *= sw[t][n] / rowsum[t*NB+n]
__global__ void scale_all_kernel(float* __restrict__ out, const float* __restrict__ swvT,
                                 const float* __restrict__ rowsumT) {
    const int n = blockIdx.x;
    const int col = blockIdx.y * 256 + threadIdx.x;
    if (col >= V) return;
#pragma unroll
    for (int t = 0; t < T; ++t) {
        float f = swvT[t * NB + n] / rowsumT[t * NB + n];
        out[((long long)n * T + t) * V + col] *= f;
    }
}

__global__ void scatter_all_kernel(float* __restrict__ out, const int* __restrict__ story,
                                   const int* __restrict__ lens, const float* __restrict__ swvT,
                                   const float* __restrict__ probfT) {
    const int n = blockIdx.x, t = blockIdx.y, b = n & 15, s = threadIdx.x;
    if (s < lens[b]) {
        int tok = story[b * S + s];
        atomicAdd(out + ((long long)n * T + t) * V + tok,
                  (1.f - swvT[t * NB + n]) * probfT[((long long)(t * NB + n)) * S + s]);
    }
}

// ---------------------------------------------------------------------------
extern "C" void kernel_launch(void* const* d_in, const int* in_sizes, int n_in,
                              void* d_out, int out_size, void* d_ws, size_t ws_size,
                              hipStream_t stream) {
    const int*   story = (const int*)d_in[0];
    const int*   lens  = (const int*)d_in[1];
    const int*   tgt   = (const int*)d_in[2];
    const int*   dom   = (const int*)d_in[3];
    const int*   sidx  = (const int*)d_in[4];
    const float* emb   = (const float*)d_in[5];
    const float* wihf  = (const float*)d_in[6];
    const float* whhf  = (const float*)d_in[7];
    const float* bihf  = (const float*)d_in[8];
    const float* bhhf  = (const float*)d_in[9];
    const float* wihb  = (const float*)d_in[10];
    const float* whhb  = (const float*)d_in[11];
    const float* bihb  = (const float*)d_in[12];
    const float* bhhb  = (const float*)d_in[13];
    const float* dwih  = (const float*)d_in[14];
    const float* dwhh  = (const float*)d_in[15];
    const float* dbih  = (const float*)d_in[16];
    const float* dbhh  = (const float*)d_in[17];
    const float* Wr    = (const float*)d_in[18];
    const float* br    = (const float*)d_in[19];
    const float* Wg    = (const float*)d_in[20];
    const float* bg    = (const float*)d_in[21];
    const float* slt   = (const float*)d_in[22];
    float* out = (float*)d_out;

    char* wsb = (char*)d_ws;
    size_t off = 0;
    auto alloc = [&](size_t bytes) -> char* {
        char* p = wsb + off;
        off += (bytes + 255) & ~(size_t)255;
        return p;
    };
    u16*   embb   = (u16*)alloc((size_t)V * H * 2);
    u16*   wihfb  = (u16*)alloc((size_t)H3 * H * 2);
    u16*   wihbb  = (u16*)alloc((size_t)H3 * H * 2);
    u16*   dwihb  = (u16*)alloc((size_t)H3 * H * 2);
    u16*   dwhhb  = (u16*)alloc((size_t)H3 * H * 2);
    u16*   wencp  = (u16*)alloc((size_t)2 * ENBLK * EROWS * EKP * 2);
    unsigned* hbuf = (unsigned*)alloc((size_t)2 * S * B * EKP * 4);   // 13.6 MB rotating
    int*   flags  = (int*)alloc((size_t)2 * S * ENBLK * 4);           // 40 KB rotating
    u16*   xb     = (u16*)alloc((size_t)S * B * H * 2);
    u16*   decinb = (u16*)alloc((size_t)T * NB * H * 2);
    float* gif    = (float*)alloc((size_t)S * B * H3 * 4);
    float* gib    = (float*)alloc((size_t)S * B * H3 * 4);
    float* dgi    = (float*)alloc((size_t)T * NB * H3 * 4);
    float* ysf    = (float*)alloc((size_t)B * S * H * 4);
    float* ysb    = (float*)alloc((size_t)B * S * H * 4);
    float* hfv    = (float*)alloc((size_t)B * H * 4);
    float* hbv    = (float*)alloc((size_t)B * H * 4);
    u16*   Eb     = (u16*)alloc((size_t)B * S * H * 2);
    u16*   ETb    = (u16*)alloc((size_t)B * H * S * 2);
    float* hf32   = (float*)alloc((size_t)NB * H * 4);
    u16*   hnk    = (u16*)alloc((size_t)NB * H * 2);
    u16*   hall   = (u16*)alloc((size_t)T * NB * H * 2);
    float* dgh    = (float*)alloc((size_t)NB * H3 * 4);
    float* probfT = (float*)alloc((size_t)T * NB * S * 4);
    float* swvT   = (float*)alloc((size_t)T * NB * 4);
    float* rowsumT = (float*)alloc((size_t)T * NB * 4);
    (void)ws_size; (void)in_sizes; (void)n_in; (void)out_size;

    auto launch_gemm = [&](const u16* A, const u16* Bt, const float* bias, float* C,
                           int M, int N, int K, int lda, int ldb, long long ldc,
                           long long sA, long long sB, long long sC, int nb,
                           int mode, float* rs) {
        dim3 g((M + 63) / 64, (N + 63) / 64, nb);
        gemm_bt<<<g, 256, 0, stream>>>(A, Bt, bias, C, M, N, K, lda, ldb, ldc,
                                       sA, sB, sC, mode, rs);
    };

    hipFuncSetAttribute((const void*)fused_step_kernel,
                        hipFuncAttributeMaxDynamicSharedMemorySize, FUSED_LDS);

    // ---- setup: casts, embeddings, input-side GEMMs -----------------------
    cvt_bf16_kernel<<<2048, 256, 0, stream>>>(emb, embb, V * H);
    cvt4_kernel<<<1024, 256, 0, stream>>>(wihf, wihb, dwih, dwhh,
                                          wihfb, wihbb, dwihb, dwhhb, H3 * H);
    {
        const int total = 2 * ENBLK * EROWS * EKP;
        prep_wenc_kernel<<<(total + 255) / 256, 256, 0, stream>>>(whhf, whhb, wencp);
    }
    embed_story_kernel<<<S * B, 256, 0, stream>>>(story, embb, xb);
    { dim3 g(NB, T); build_decin_kernel<<<g, 256, 0, stream>>>(tgt, dom, sidx, slt, embb, decinb); }

    launch_gemm(xb, wihfb, bihf, gif, S * B, H3, H, H, H, H3, 0, 0, 0, 1, 0, nullptr);
    launch_gemm(xb, wihbb, bihb, gib, S * B, H3, H, H, H, H3, 0, 0, 0, 1, 0, nullptr);
    launch_gemm(decinb, dwihb, dbih, dgi, T * NB, H3, H, H, H, H3, 0, 0, 0, 1, 0, nullptr);

    // ---- encoder recurrence (protocol v6: rotating buffers, no fences) ----
    hipMemsetAsync(flags, 0, (size_t)2 * S * ENBLK * 4, stream);
    hipMemsetAsync(hbuf, 0, (size_t)2 * S * B * EKP * 4, stream);
    hipMemsetAsync(rowsumT, 0, (size_t)T * NB * 4, stream);
    enc_rnn2_kernel<<<2 * ENBLK, 256, 0, stream>>>(wencp, bhhf, bhhb, gif, gib, lens,
                                                   hbuf, flags, ysf, ysb, hfv, hbv);
    { dim3 g(B, S / 32); packE_kernel<<<g, 256, 0, stream>>>(ysf, ysb, Eb, ETb); }
    h0_kernel<<<NB, 256, 0, stream>>>(hfv, hbv, hf32, hnk);

    // ---- decoder: sequential chain (2 launches/step) ----------------------
    for (int t = 0; t < T; ++t) {
        const u16* hprev = (t == 0) ? hnk : hall + (size_t)(t - 1) * NB * H;
        launch_gemm(hprev, dwhhb, dbhh, dgh, NB, H3, H, H, H, H3, 0, 0, 0, 1, 0, nullptr);
        fused_step_kernel<<<16, 512, FUSED_LDS, stream>>>(
            dgi, dgh, hf32, hall, decinb, Eb, ETb, lens, Wr, br, Wg, bg,
            probfT, swvT, out + (size_t)NB * T * V, t);
    }

    // ---- batched vocab projection: one GEMM over all (t, n) rows ----------
    launch_gemm(hall, embb, nullptr, out, T * NB, V, H, H, H, V,
                0, 0, 0, 1, 2, rowsumT);
    { dim3 g(NB, (V + 255) / 256); scale_all_kernel<<<g, 256, 0, stream>>>(out, swvT, rowsumT); }
    { dim3 g(NB, T); scatter_all_kernel<<<g, 256, 0, stream>>>(out, story, lens, swvT, probfT); }
}